// Round 13
// baseline (234.311 us; speedup 1.0000x reference)
//
#include <hip/hip_runtime.h>
#include <cstddef>

typedef unsigned short u16;
typedef unsigned char u8;
typedef unsigned u32;
typedef float f32x4 __attribute__((ext_vector_type(4)));
typedef u16 u16x4 __attribute__((ext_vector_type(4)));
typedef u16 u16x8 __attribute__((ext_vector_type(8)));
typedef u8 u8x8 __attribute__((ext_vector_type(8)));
typedef __bf16 bf16x8 __attribute__((ext_vector_type(8)));
typedef int i32x4 __attribute__((ext_vector_type(4)));
typedef int i32x8 __attribute__((ext_vector_type(8)));

__device__ __forceinline__ u16 f2bf(float f) {
  u32 u = __builtin_bit_cast(u32, f);
  u += 0x7fffu + ((u >> 16) & 1u);   // RTNE
  return (u16)(u >> 16);
}
__device__ __forceinline__ float bf2f(u16 h) {
  return __builtin_bit_cast(float, ((u32)h) << 16);
}
__device__ __forceinline__ u8 f2fp8(float v) {
  int t = __builtin_amdgcn_cvt_pk_fp8_f32(v, v, 0, false);
  return (u8)(t & 0xff);
}
__device__ __forceinline__ void gld_lds16(const void* g, void* l) {
  __builtin_amdgcn_global_load_lds((const __attribute__((address_space(1))) void*)g,
                                   (__attribute__((address_space(3))) void*)l, 16, 0, 0);
}

// ---------------- all f32->bf16 converts in ONE launch ----------------
__global__ __launch_bounds__(256) void cvt_all(
    const float* __restrict__ q, const float* __restrict__ k, const float* __restrict__ v,
    const float* __restrict__ w5, const float* __restrict__ w3,
    const float* __restrict__ w7, const float* __restrict__ w9,
    u16* __restrict__ o_q, u16* __restrict__ o_k, u16* __restrict__ o_v,
    u16* __restrict__ o_wq, u16* __restrict__ o_wk, u16* __restrict__ o_wv,
    u16* __restrict__ o_ow)
{
  int b = blockIdx.x;
  const float* in; u16* out; int base; bool perm = false;
  if      (b < 512)  { in = q;  out = o_q;  base = b; }
  else if (b < 1024) { in = k;  out = o_k;  base = b - 512; }
  else if (b < 1536) { in = v;  out = o_v;  base = b - 1024; }
  else if (b < 2560) { in = w5; out = o_wq; base = b - 1536; }
  else if (b < 3584) { in = w3; out = o_wk; base = b - 2560; }
  else if (b < 4608) { in = w7; out = o_wv; base = b - 3584; }
  else               { in = w9; out = o_ow; base = b - 4608; perm = true; }
  int i = (base * 256 + threadIdx.x) * 8;
  u16x8 o;
  if (!perm) {
    f32x4 a = *(const f32x4*)(in + i);
    f32x4 c = *(const f32x4*)(in + i + 4);
    o[0] = f2bf(a[0]); o[1] = f2bf(a[1]); o[2] = f2bf(a[2]); o[3] = f2bf(a[3]);
    o[4] = f2bf(c[0]); o[5] = f2bf(c[1]); o[6] = f2bf(c[2]); o[7] = f2bf(c[3]);
  } else {
    // within-64 K-group permutation: pos t <- true (t&3)*16+(t>>2)
    int row = i >> 12, col0 = i & 4095;
    int group = col0 & ~63, t0 = col0 & 63;
    const float* rp = in + ((size_t)row << 12) + group;
#pragma unroll
    for (int j = 0; j < 8; ++j) {
      int t = t0 + j;
      o[j] = f2bf(rp[((t & 3) << 4) + (t >> 2)]);
    }
  }
  *(u16x8*)(out + i) = o;
}

// =====================================================================
// bf16 pipelined 128x128 B^T GEMM — ALL THREE projections, one launch.
// (unchanged from round 12 — passing, issue-early staging, K-tile 32)
// =====================================================================
__global__ __launch_bounds__(256, 2) void gemm_proj(
    const u16* __restrict__ Aq, const u16* __restrict__ Ak, const u16* __restrict__ Av,
    const u16* __restrict__ Bq, const u16* __restrict__ Bk, const u16* __restrict__ Bv,
    u8* __restrict__ Cq, u8* __restrict__ Ck, u8* __restrict__ Cvv,
    const float* __restrict__ bq, const float* __restrict__ bk, const float* __restrict__ bv,
    int N, int K)
{
  __shared__ alignas(16) char smem[33024];

  const int tid = threadIdx.x, lid = tid & 63, wid = tid >> 6;
  const int wm = wid >> 1, wn = wid & 1;
  const int g = lid >> 4, r16 = lid & 15;
  const int which = blockIdx.z;

  const u16* A = (which == 0) ? Aq : (which == 1) ? Ak : Av;
  const u16* B = (which == 0) ? Bq : (which == 1) ? Bk : Bv;
  u8* C = (which == 0) ? Cq : (which == 1) ? Ck : Cvv;
  const float* bias = (which == 0) ? bq : (which == 1) ? bk : bv;

  const int nx = gridDim.x, ny = gridDim.y;
  const int lin = blockIdx.x + nx * blockIdx.y;
  const int xcd = lin & 7, slot = lin >> 3;
  const int wx = slot % nx;
  const int c_ = xcd + (slot / nx) * 8;
  const int m0 = (c_ % ny) * 128, n0 = wx * 128;

  const int NT = K >> 5;

  int offA[4], offB[4];
#pragma unroll
  for (int f = 0; f < 4; ++f) {
    int ra = wm * 64 + f * 16 + r16;
    offA[f] = ra * 64 + ((g ^ ((ra >> 1) & 3)) << 4);
    int rb = wn * 64 + f * 16 + r16;
    offB[f] = rb * 64 + ((g ^ ((rb >> 1) & 3)) << 4);
  }

  auto stage_tile = [&](int ts) {
    char* base = smem + (ts & 1) * 16384;
    const u16* At = A + (size_t)ts * 32;
    const u16* Bt = B + (size_t)ts * 32;
#pragma unroll
    for (int l = 0; l < 2; ++l) {
      int i = l * 256 + tid;
      int row = i >> 2, x = i & 3;
      int c = x ^ ((row >> 1) & 3);
      gld_lds16(At + (size_t)(m0 + row) * K + c * 8, base + i * 16);
    }
#pragma unroll
    for (int l = 0; l < 2; ++l) {
      int i = l * 256 + tid;
      int row = i >> 2, x = i & 3;
      int c = x ^ ((row >> 1) & 3);
      gld_lds16(Bt + (size_t)(n0 + row) * K + c * 8, base + 8192 + i * 16);
    }
  };

  f32x4 acc[4][4];
#pragma unroll
  for (int i = 0; i < 4; ++i)
#pragma unroll
    for (int j = 0; j < 4; ++j) acc[i][j] = 0.0f;

  stage_tile(0);
  stage_tile(1);
  asm volatile("s_waitcnt vmcnt(4)" ::: "memory");
  __builtin_amdgcn_s_barrier();

  for (int t = 0; t < NT; ++t) {
    const char* Ab = smem + (t & 1) * 16384;
    const char* Bb = Ab + 8192;
    bf16x8 ar[4], br[4];
#pragma unroll
    for (int f = 0; f < 4; ++f) ar[f] = *(const bf16x8*)(Ab + offA[f]);
#pragma unroll
    for (int f = 0; f < 4; ++f) br[f] = *(const bf16x8*)(Bb + offB[f]);
    asm volatile("s_waitcnt lgkmcnt(0)" ::: "memory");
    __builtin_amdgcn_s_barrier();
    if (t + 2 < NT) stage_tile(t + 2);
    __builtin_amdgcn_s_setprio(1);
#pragma unroll
    for (int mf = 0; mf < 4; ++mf)
#pragma unroll
      for (int nf = 0; nf < 4; ++nf)
        acc[mf][nf] = __builtin_amdgcn_mfma_f32_16x16x32_bf16(ar[mf], br[nf], acc[mf][nf], 0, 0, 0);
    __builtin_amdgcn_s_setprio(0);
    if (t + 2 < NT) asm volatile("s_waitcnt vmcnt(4)" ::: "memory");
    else            asm volatile("s_waitcnt vmcnt(0)" ::: "memory");
    __builtin_amdgcn_s_barrier();
  }

  if (which < 2) {
    const int hh = (n0 + wn * 64) >> 9;
    const int d2g = (n0 & 511) + wn * 64;
#pragma unroll
    for (int mf = 0; mf < 4; ++mf)
#pragma unroll
      for (int r = 0; r < 4; ++r) {
        int gm = m0 + wm * 64 + mf * 16 + (g << 2) + r;
        int b = gm >> 9, s = gm & 511;
        float v0 = acc[mf][0][r] + bias[n0 + wn * 64 + 0 * 16 + r16];
        float v1 = acc[mf][1][r] + bias[n0 + wn * 64 + 1 * 16 + r16];
        float v2 = acc[mf][2][r] + bias[n0 + wn * 64 + 2 * 16 + r16];
        float v3 = acc[mf][3][r] + bias[n0 + wn * 64 + 3 * 16 + r16];
        int pk = __builtin_amdgcn_cvt_pk_fp8_f32(v0, v1, 0, false);
        pk = __builtin_amdgcn_cvt_pk_fp8_f32(v2, v3, pk, true);
        int row = (which == 0) ? ((s << 3) + hh) : ((hh << 9) + s);
        *(u32*)(C + (size_t)b * 2097152 + (size_t)row * 512 + d2g + r16 * 4) = (u32)pk;
      }
  } else {
    u16* E = (u16*)smem;   // 128 x 129 bf16
#pragma unroll
    for (int mf = 0; mf < 4; ++mf)
#pragma unroll
      for (int nf = 0; nf < 4; ++nf)
#pragma unroll
        for (int r = 0; r < 4; ++r) {
          int lm = wm * 64 + mf * 16 + (g << 2) + r;
          int ln = wn * 64 + nf * 16 + r16;
          E[lm * 129 + ln] = f2bf(acc[mf][nf][r] + bias[n0 + ln]);
        }
    __syncthreads();
    int b = m0 >> 9, s0 = m0 & 511, hh = n0 >> 9, d20 = n0 & 511;
    int c = tid >> 1;
    int r0 = (tid & 1) * 64;
    u8* dst = C + (size_t)b * 2097152 + (size_t)(d20 + c) * 4096 + (hh << 9) + s0 + r0;
#pragma unroll
    for (int i = 0; i < 64; i += 8) {
      u8x8 p;
#pragma unroll
      for (int jj = 0; jj < 8; ++jj) {
        int t = i + jj;
        int sl = r0 + ((t & 3) << 4) + (t >> 2);
        p[jj] = f2fp8(bf2f(E[sl * 129 + c]));
      }
      *(u8x8*)(dst + i) = p;
    }
  }
}

// =====================================================================
// MX-scaled fp8 pipelined 128x128 B^T GEMM (scores / PV).
// mfma_scale_f32_16x16x128_f8f6f4, unit E8M0 scales (exact 1.0) -> 2.27x
// the non-scaled fp8 rate, same e4m3 operands, same 16x16 C/D layout.
// 512 thr, 8 waves (4M x 2N), per-wave 32x64. K-tile 128 B, NT=K/128.
// LDS 2 x 32KB = 64KB -> 2 blk/CU (16 waves/CU, same as before).
// Frag: lane holds row (l&15), k-bytes [(l>>4)*32,+32) as 2 b128 reads.
// Swizzle (128B rows): slot s_phys = s_log ^ (row&7) -> 2-way max (free);
// staged with inverse-permuted global source (linear gld_lds dest).
// EPI: 6 scores  P(u8, kv-permuted packed u32) = exp(s*scale), rowsum L
//      7 PV      O = (P@V)/L -> oflat bf16 (packed u16x4, K-permuted)
// =====================================================================
template<int EPI>
__global__ __launch_bounds__(512, 4) void gemm_mx(
    const u8* __restrict__ A, const u8* __restrict__ B, void* __restrict__ Cv,
    float* __restrict__ Lbuf, int N, int K, float scale,
    long bsA, long bsB, long bsC)
{
  __shared__ alignas(16) char smem[65536];

  const int tid = threadIdx.x, lid = tid & 63, wid = tid >> 6;
  const int wm = wid >> 1, wn = wid & 1;     // 4 x 2 wave grid
  const int g = lid >> 4, r16 = lid & 15;

  const int nx = gridDim.x, ny = gridDim.y;
  const int lin = blockIdx.x + nx * (blockIdx.y + ny * blockIdx.z);
  const int xcd = lin & 7, slot = lin >> 3;
  const int wx = slot % nx;
  const int c_ = xcd + (slot / nx) * 8;
  const int m0 = (c_ % ny) * 128, n0 = wx * 128, z = c_ / ny;

  A += (size_t)z * bsA;
  B += (size_t)z * bsB;
  const int NT = K >> 7;   // K-tile = 128 bytes

  // frag byte offsets: row r, logical 16B-slots {2g, 2g+1}; phys = log ^ (r&7)
  int offA[2][2], offB[4][2];
#pragma unroll
  for (int f = 0; f < 2; ++f) {
    int ra = wm * 32 + f * 16 + r16;
    offA[f][0] = ra * 128 + (((2 * g)     ^ (ra & 7)) << 4);
    offA[f][1] = ra * 128 + (((2 * g + 1) ^ (ra & 7)) << 4);
  }
#pragma unroll
  for (int f = 0; f < 4; ++f) {
    int rb = wn * 64 + f * 16 + r16;
    offB[f][0] = rb * 128 + (((2 * g)     ^ (rb & 7)) << 4);
    offB[f][1] = rb * 128 + (((2 * g + 1) ^ (rb & 7)) << 4);
  }

  auto stage_tile = [&](int ts) {
    char* base = smem + (ts & 1) * 32768;
    const u8* At = A + (size_t)ts * 128;
    const u8* Bt = B + (size_t)ts * 128;
#pragma unroll
    for (int l = 0; l < 2; ++l) {
      int i = l * 512 + tid;
      int row = i >> 3, sp = i & 7;
      int sl = sp ^ (row & 7);               // logical chunk held by phys slot
      gld_lds16(At + (size_t)(m0 + row) * K + sl * 16, base + i * 16);
    }
#pragma unroll
    for (int l = 0; l < 2; ++l) {
      int i = l * 512 + tid;
      int row = i >> 3, sp = i & 7;
      int sl = sp ^ (row & 7);
      gld_lds16(Bt + (size_t)(n0 + row) * K + sl * 16, base + 16384 + i * 16);
    }
  };

  f32x4 acc[2][4];
#pragma unroll
  for (int i = 0; i < 2; ++i)
#pragma unroll
    for (int j = 0; j < 4; ++j) acc[i][j] = 0.0f;

  stage_tile(0);
  stage_tile(1);
  asm volatile("s_waitcnt vmcnt(4)" ::: "memory");
  __builtin_amdgcn_s_barrier();

  for (int t = 0; t < NT; ++t) {
    const char* Ab = smem + (t & 1) * 32768;
    const char* Bb = Ab + 16384;
    i32x8 af[2], bfr[4];
#pragma unroll
    for (int f = 0; f < 2; ++f) {
      i32x4 lo = *(const i32x4*)(Ab + offA[f][0]);
      i32x4 hi = *(const i32x4*)(Ab + offA[f][1]);
      af[f] = __builtin_shufflevector(lo, hi, 0, 1, 2, 3, 4, 5, 6, 7);
    }
#pragma unroll
    for (int f = 0; f < 4; ++f) {
      i32x4 lo = *(const i32x4*)(Bb + offB[f][0]);
      i32x4 hi = *(const i32x4*)(Bb + offB[f][1]);
      bfr[f] = __builtin_shufflevector(lo, hi, 0, 1, 2, 3, 4, 5, 6, 7);
    }
    asm volatile("s_waitcnt lgkmcnt(0)" ::: "memory");
    __builtin_amdgcn_s_barrier();
    if (t + 2 < NT) stage_tile(t + 2);       // issue overlaps MFMA below
    __builtin_amdgcn_s_setprio(1);
#pragma unroll
    for (int mf = 0; mf < 2; ++mf)
#pragma unroll
      for (int nf = 0; nf < 4; ++nf)
        acc[mf][nf] = __builtin_amdgcn_mfma_scale_f32_16x16x128_f8f6f4(
            af[mf], bfr[nf], acc[mf][nf],
            0 /*cbsz: A=fp8*/, 0 /*blgp: B=fp8*/,
            0, 0x7F7F7F7F /*scaleA = 1.0*/, 0, 0x7F7F7F7F /*scaleB = 1.0*/);
    __builtin_amdgcn_s_setprio(0);
    if (t + 2 < NT) asm volatile("s_waitcnt vmcnt(4)" ::: "memory");
    else            asm volatile("s_waitcnt vmcnt(0)" ::: "memory");
    __builtin_amdgcn_s_barrier();
  }

  if constexpr (EPI == 6) {
    // P = exp(s*scale) -> fp8, kv-permuted packed u32; rowsum L via shfl+atomic
    u8* Cp = (u8*)Cv + (size_t)z * bsC;
    float* Lp = Lbuf + (size_t)z * 4096;
#pragma unroll
    for (int mf = 0; mf < 2; ++mf) {
#pragma unroll
      for (int r = 0; r < 4; ++r) {
        int gm = m0 + wm * 32 + mf * 16 + (g << 2) + r;
        float p0 = __expf(acc[mf][0][r] * scale);
        float p1 = __expf(acc[mf][1][r] * scale);
        float p2 = __expf(acc[mf][2][r] * scale);
        float p3 = __expf(acc[mf][3][r] * scale);
        float rs = (p0 + p1) + (p2 + p3);
        int pk = __builtin_amdgcn_cvt_pk_fp8_f32(p0, p1, 0, false);
        pk = __builtin_amdgcn_cvt_pk_fp8_f32(p2, p3, pk, true);
        *(u32*)(Cp + (size_t)gm * N + n0 + wn * 64 + r16 * 4) = (u32)pk;
        rs += __shfl_xor(rs, 1); rs += __shfl_xor(rs, 2);
        rs += __shfl_xor(rs, 4); rs += __shfl_xor(rs, 8);
        if (r16 == 0) atomicAdd(&Lp[gm], rs);
      }
    }
  } else {
    // PV: O = acc / L[row] -> oflat bf16, packed u16x4, cols within-64 permuted
    u16* C = (u16*)Cv + (size_t)z * bsC;
    const float* Lp = Lbuf + (size_t)z * 4096;
#pragma unroll
    for (int mf = 0; mf < 2; ++mf) {
#pragma unroll
      for (int r = 0; r < 4; ++r) {
        int gm = m0 + wm * 32 + mf * 16 + (g << 2) + r;
        float inv = 1.0f / Lp[gm];
        u16x4 o;
#pragma unroll
        for (int nf = 0; nf < 4; ++nf) o[nf] = f2bf(acc[mf][nf][r] * inv);
        *(u16x4*)(C + (size_t)(gm >> 3) * 4096 + (size_t)(gm & 7) * 512 +
                  n0 + wn * 64 + r16 * 4) = o;
      }
    }
  }
}

// ---------------- final projection, bf16 in, f32+bias out, 64x64 tile ----------------
__global__ __launch_bounds__(256) void gemm_bt_final(
    const u16* __restrict__ A, const u16* __restrict__ B, float* __restrict__ C,
    const float* __restrict__ bias, int N, int K)
{
  constexpr int BM = 64, BN = 64, BK = 64;
  __shared__ alignas(16) char smem[(BM + BN) * BK * 2];
  u16* As = (u16*)smem;
  u16* Bs = As + BM * BK;

  const int tid = threadIdx.x;
  const int lid = tid & 63, wid = tid >> 6;
  const int m0 = blockIdx.y * BM, n0 = blockIdx.x * BN;
  const int wm = wid >> 1, wn = wid & 1;

  f32x4 acc[2][2];
#pragma unroll
  for (int i = 0; i < 2; ++i)
#pragma unroll
    for (int j = 0; j < 2; ++j) acc[i][j] = 0.0f;

  const int rA = lid >> 3;
  const int ke = (lid & 7) * 8;

  const int nK = K / BK;
  for (int kt = 0; kt < nK; ++kt) {
    const int k0 = kt * BK;
#pragma unroll
    for (int c = 0; c < 2; ++c) {
      int chunk = wid * 2 + c;
      gld_lds16(A + (size_t)(m0 + chunk * 8 + rA) * K + k0 + ke, (char*)As + chunk * 1024);
    }
#pragma unroll
    for (int c = 0; c < 2; ++c) {
      int chunk = wid * 2 + c;
      gld_lds16(B + (size_t)(n0 + chunk * 8 + rA) * K + k0 + ke, (char*)Bs + chunk * 1024);
    }
    __syncthreads();
#pragma unroll
    for (int kc = 0; kc < 2; ++kc) {
      bf16x8 af[2], bfv[2];
      const int kb = kc * 32 + (lid >> 4) * 8;
#pragma unroll
      for (int i = 0; i < 2; ++i)
        af[i] = *(const bf16x8*)&As[(wm * 32 + i * 16 + (lid & 15)) * BK + kb];
#pragma unroll
      for (int j = 0; j < 2; ++j)
        bfv[j] = *(const bf16x8*)&Bs[(wn * 32 + j * 16 + (lid & 15)) * BK + kb];
#pragma unroll
      for (int i = 0; i < 2; ++i)
#pragma unroll
        for (int j = 0; j < 2; ++j)
          acc[i][j] = __builtin_amdgcn_mfma_f32_16x16x32_bf16(af[i], bfv[j], acc[i][j], 0, 0, 0);
    }
    __syncthreads();
  }

#pragma unroll
  for (int i = 0; i < 2; ++i)
#pragma unroll
    for (int j = 0; j < 2; ++j)
#pragma unroll
      for (int r = 0; r < 4; ++r) {
        int gm = m0 + wm * 32 + i * 16 + ((lid >> 4) << 2) + r;
        int gn = n0 + wn * 32 + j * 16 + (lid & 15);
        C[(size_t)gm * N + gn] = acc[i][j][r] + bias[gn];
      }
}

// ---------------------------------------------------------------------------
extern "C" void kernel_launch(void* const* d_in, const int* in_sizes, int n_in,
                              void* d_out, int out_size, void* d_ws, size_t ws_size,
                              hipStream_t stream) {
  (void)in_sizes; (void)n_in; (void)out_size; (void)ws_size;
  const float* q_f  = (const float*)d_in[0];
  const float* k_f  = (const float*)d_in[1];
  const float* v_f  = (const float*)d_in[2];
  const float* wq_b = (const float*)d_in[4];
  const float* wk_b = (const float*)d_in[6];
  const float* wv_b = (const float*)d_in[8];
  const float* ou_b = (const float*)d_in[10];
  float* out = (float*)d_out;

  char* ws = (char*)d_ws;
  u16* q_bf  = (u16*)(ws + 0);          // 2MB  bf16(q)
  u16* k_bf  = (u16*)(ws + 2097152);    // 2MB
  u16* v_bf  = (u16*)(ws + 4194304);    // 2MB
  u16* wA_q  = (u16*)(ws + 6291456);    // 4MB  bf16(wk_w) (reference swap)
  u16* wA_k  = (u16*)(ws + 10485760);   // 4MB  bf16(wq_w)
  u16* wA_v  = (u16*)(ws + 14680064);   // 4MB  bf16(wv_w)
  u16* ow_bf = (u16*)(ws + 18874368);   // 4MB  bf16(out_w), K within-64 permuted
  u8*  qp    = (u8*)(ws + 23068672);    // 8MB  (4,4096,512) fp8, l=s*8+h, d2 permuted
  u8*  kp    = (u8*)(ws + 31457280);    // 8MB  (4,4096,512) fp8, l'=h*512+s, d2 permuted
  u8*  vpt   = (u8*)(ws + 39845888);    // 8MB  (4,512,4096) fp8, [d2][kv-permuted]
  u16* oflat = (u16*)(ws + 48234496);   // 16MB (4,512,4096) bf16, cols within-64 permuted
  u8*  P     = (u8*)(ws + 65011712);    // 64MB (4,4096,4096) fp8, cols kv-permuted

  float* L = (float*)d_out;  // 64KB row-sums; dead until final GEMM overwrites

  // all converts in one launch
  cvt_all<<<5632, 256, 0, stream>>>(
      q_f, k_f, v_f, (const float*)d_in[5], (const float*)d_in[3],
      (const float*)d_in[7], (const float*)d_in[9],
      q_bf, k_bf, v_bf, wA_q, wA_k, wA_v, ow_bf);

  // all three projections in one launch (reference swap: qp uses wk, kp uses wq)
  gemm_proj<<<dim3(32,16,3), 256, 0, stream>>>(
      q_bf, k_bf, v_bf, wA_q, wA_k, wA_v, qp, kp, vpt, wk_b, wq_b, wv_b, 4096, 512);

  const float scl = 0.04419417382415922f;  // 1/sqrt(512)
  hipMemsetAsync(L, 0, 65536, stream);
  // scores: P = exp(s*scl) fp8 (kv-permuted) + row-sums into L  (MX fp8, K=128)
  gemm_mx<6><<<dim3(32,32,4), 512, 0, stream>>>(qp, kp, P, L, 4096, 512, scl,
                                                2097152, 2097152, 16777216);
  // PV: O = (P @ V) / L -> oflat bf16  (MX fp8, K=128, NT=32)
  gemm_mx<7><<<dim3(4,32,4), 512, 0, stream>>>(P, vpt, oflat, L, 512, 4096, 1.f,
                                               16777216, 2097152, 2097152);
  // final projection, bf16 -> f32 + bias (oflat & ow_bf share the K permutation)
  gemm_bt_final<<<dim3(8,32,1), 256, 0, stream>>>(oflat, ow_bf, out, ou_b, 512, 4096);
}

// Round 14
// 226.934 us; speedup vs baseline: 1.0325x; 1.0325x over previous
//
#include <hip/hip_runtime.h>
#include <cstddef>

typedef unsigned short u16;
typedef unsigned char u8;
typedef unsigned u32;
typedef float f32x4 __attribute__((ext_vector_type(4)));
typedef u16 u16x4 __attribute__((ext_vector_type(4)));
typedef u16 u16x8 __attribute__((ext_vector_type(8)));
typedef u8 u8x8 __attribute__((ext_vector_type(8)));
typedef __bf16 bf16x8 __attribute__((ext_vector_type(8)));
typedef int i32x4 __attribute__((ext_vector_type(4)));
typedef int i32x8 __attribute__((ext_vector_type(8)));

__device__ __forceinline__ u16 f2bf(float f) {
  u32 u = __builtin_bit_cast(u32, f);
  u += 0x7fffu + ((u >> 16) & 1u);   // RTNE
  return (u16)(u >> 16);
}
__device__ __forceinline__ float bf2f(u16 h) {
  return __builtin_bit_cast(float, ((u32)h) << 16);
}
__device__ __forceinline__ u8 f2fp8(float v) {
  int t = __builtin_amdgcn_cvt_pk_fp8_f32(v, v, 0, false);
  return (u8)(t & 0xff);
}
__device__ __forceinline__ void gld_lds16(const void* g, void* l) {
  __builtin_amdgcn_global_load_lds((const __attribute__((address_space(1))) void*)g,
                                   (__attribute__((address_space(3))) void*)l, 16, 0, 0);
}

// ---------------- all f32->bf16 converts in ONE launch ----------------
__global__ __launch_bounds__(256) void cvt_all(
    const float* __restrict__ q, const float* __restrict__ k, const float* __restrict__ v,
    const float* __restrict__ w5, const float* __restrict__ w3,
    const float* __restrict__ w7, const float* __restrict__ w9,
    u16* __restrict__ o_q, u16* __restrict__ o_k, u16* __restrict__ o_v,
    u16* __restrict__ o_wq, u16* __restrict__ o_wk, u16* __restrict__ o_wv,
    u16* __restrict__ o_ow)
{
  int b = blockIdx.x;
  const float* in; u16* out; int base; bool perm = false;
  if      (b < 512)  { in = q;  out = o_q;  base = b; }
  else if (b < 1024) { in = k;  out = o_k;  base = b - 512; }
  else if (b < 1536) { in = v;  out = o_v;  base = b - 1024; }
  else if (b < 2560) { in = w5; out = o_wq; base = b - 1536; }
  else if (b < 3584) { in = w3; out = o_wk; base = b - 2560; }
  else if (b < 4608) { in = w7; out = o_wv; base = b - 3584; }
  else               { in = w9; out = o_ow; base = b - 4608; perm = true; }
  int i = (base * 256 + threadIdx.x) * 8;
  u16x8 o;
  if (!perm) {
    f32x4 a = *(const f32x4*)(in + i);
    f32x4 c = *(const f32x4*)(in + i + 4);
    o[0] = f2bf(a[0]); o[1] = f2bf(a[1]); o[2] = f2bf(a[2]); o[3] = f2bf(a[3]);
    o[4] = f2bf(c[0]); o[5] = f2bf(c[1]); o[6] = f2bf(c[2]); o[7] = f2bf(c[3]);
  } else {
    // within-64 K-group permutation: pos t <- true (t&3)*16+(t>>2)
    int row = i >> 12, col0 = i & 4095;
    int group = col0 & ~63, t0 = col0 & 63;
    const float* rp = in + ((size_t)row << 12) + group;
#pragma unroll
    for (int j = 0; j < 8; ++j) {
      int t = t0 + j;
      o[j] = f2bf(rp[((t & 3) << 4) + (t >> 2)]);
    }
  }
  *(u16x8*)(out + i) = o;
}

// =====================================================================
// bf16 pipelined 128x128 B^T GEMM — ALL THREE projections, one launch.
// (unchanged — passing, issue-early staging, K-tile 32)
// =====================================================================
__global__ __launch_bounds__(256, 2) void gemm_proj(
    const u16* __restrict__ Aq, const u16* __restrict__ Ak, const u16* __restrict__ Av,
    const u16* __restrict__ Bq, const u16* __restrict__ Bk, const u16* __restrict__ Bv,
    u8* __restrict__ Cq, u8* __restrict__ Ck, u8* __restrict__ Cvv,
    const float* __restrict__ bq, const float* __restrict__ bk, const float* __restrict__ bv,
    int N, int K)
{
  __shared__ alignas(16) char smem[33024];

  const int tid = threadIdx.x, lid = tid & 63, wid = tid >> 6;
  const int wm = wid >> 1, wn = wid & 1;
  const int g = lid >> 4, r16 = lid & 15;
  const int which = blockIdx.z;

  const u16* A = (which == 0) ? Aq : (which == 1) ? Ak : Av;
  const u16* B = (which == 0) ? Bq : (which == 1) ? Bk : Bv;
  u8* C = (which == 0) ? Cq : (which == 1) ? Ck : Cvv;
  const float* bias = (which == 0) ? bq : (which == 1) ? bk : bv;

  const int nx = gridDim.x, ny = gridDim.y;
  const int lin = blockIdx.x + nx * blockIdx.y;
  const int xcd = lin & 7, slot = lin >> 3;
  const int wx = slot % nx;
  const int c_ = xcd + (slot / nx) * 8;
  const int m0 = (c_ % ny) * 128, n0 = wx * 128;

  const int NT = K >> 5;

  int offA[4], offB[4];
#pragma unroll
  for (int f = 0; f < 4; ++f) {
    int ra = wm * 64 + f * 16 + r16;
    offA[f] = ra * 64 + ((g ^ ((ra >> 1) & 3)) << 4);
    int rb = wn * 64 + f * 16 + r16;
    offB[f] = rb * 64 + ((g ^ ((rb >> 1) & 3)) << 4);
  }

  auto stage_tile = [&](int ts) {
    char* base = smem + (ts & 1) * 16384;
    const u16* At = A + (size_t)ts * 32;
    const u16* Bt = B + (size_t)ts * 32;
#pragma unroll
    for (int l = 0; l < 2; ++l) {
      int i = l * 256 + tid;
      int row = i >> 2, x = i & 3;
      int c = x ^ ((row >> 1) & 3);
      gld_lds16(At + (size_t)(m0 + row) * K + c * 8, base + i * 16);
    }
#pragma unroll
    for (int l = 0; l < 2; ++l) {
      int i = l * 256 + tid;
      int row = i >> 2, x = i & 3;
      int c = x ^ ((row >> 1) & 3);
      gld_lds16(Bt + (size_t)(n0 + row) * K + c * 8, base + 8192 + i * 16);
    }
  };

  f32x4 acc[4][4];
#pragma unroll
  for (int i = 0; i < 4; ++i)
#pragma unroll
    for (int j = 0; j < 4; ++j) acc[i][j] = 0.0f;

  stage_tile(0);
  stage_tile(1);
  asm volatile("s_waitcnt vmcnt(4)" ::: "memory");
  __builtin_amdgcn_s_barrier();

  for (int t = 0; t < NT; ++t) {
    const char* Ab = smem + (t & 1) * 16384;
    const char* Bb = Ab + 8192;
    bf16x8 ar[4], br[4];
#pragma unroll
    for (int f = 0; f < 4; ++f) ar[f] = *(const bf16x8*)(Ab + offA[f]);
#pragma unroll
    for (int f = 0; f < 4; ++f) br[f] = *(const bf16x8*)(Bb + offB[f]);
    asm volatile("s_waitcnt lgkmcnt(0)" ::: "memory");
    __builtin_amdgcn_s_barrier();
    if (t + 2 < NT) stage_tile(t + 2);
    __builtin_amdgcn_s_setprio(1);
#pragma unroll
    for (int mf = 0; mf < 4; ++mf)
#pragma unroll
      for (int nf = 0; nf < 4; ++nf)
        acc[mf][nf] = __builtin_amdgcn_mfma_f32_16x16x32_bf16(ar[mf], br[nf], acc[mf][nf], 0, 0, 0);
    __builtin_amdgcn_s_setprio(0);
    if (t + 2 < NT) asm volatile("s_waitcnt vmcnt(4)" ::: "memory");
    else            asm volatile("s_waitcnt vmcnt(0)" ::: "memory");
    __builtin_amdgcn_s_barrier();
  }

  if (which < 2) {
    const int hh = (n0 + wn * 64) >> 9;
    const int d2g = (n0 & 511) + wn * 64;
#pragma unroll
    for (int mf = 0; mf < 4; ++mf)
#pragma unroll
      for (int r = 0; r < 4; ++r) {
        int gm = m0 + wm * 64 + mf * 16 + (g << 2) + r;
        int b = gm >> 9, s = gm & 511;
        float v0 = acc[mf][0][r] + bias[n0 + wn * 64 + 0 * 16 + r16];
        float v1 = acc[mf][1][r] + bias[n0 + wn * 64 + 1 * 16 + r16];
        float v2 = acc[mf][2][r] + bias[n0 + wn * 64 + 2 * 16 + r16];
        float v3 = acc[mf][3][r] + bias[n0 + wn * 64 + 3 * 16 + r16];
        int pk = __builtin_amdgcn_cvt_pk_fp8_f32(v0, v1, 0, false);
        pk = __builtin_amdgcn_cvt_pk_fp8_f32(v2, v3, pk, true);
        int row = (which == 0) ? ((s << 3) + hh) : ((hh << 9) + s);
        *(u32*)(C + (size_t)b * 2097152 + (size_t)row * 512 + d2g + r16 * 4) = (u32)pk;
      }
  } else {
    u16* E = (u16*)smem;   // 128 x 129 bf16
#pragma unroll
    for (int mf = 0; mf < 4; ++mf)
#pragma unroll
      for (int nf = 0; nf < 4; ++nf)
#pragma unroll
        for (int r = 0; r < 4; ++r) {
          int lm = wm * 64 + mf * 16 + (g << 2) + r;
          int ln = wn * 64 + nf * 16 + r16;
          E[lm * 129 + ln] = f2bf(acc[mf][nf][r] + bias[n0 + ln]);
        }
    __syncthreads();
    int b = m0 >> 9, s0 = m0 & 511, hh = n0 >> 9, d20 = n0 & 511;
    int c = tid >> 1;
    int r0 = (tid & 1) * 64;
    u8* dst = C + (size_t)b * 2097152 + (size_t)(d20 + c) * 4096 + (hh << 9) + s0 + r0;
#pragma unroll
    for (int i = 0; i < 64; i += 8) {
      u8x8 p;
#pragma unroll
      for (int jj = 0; jj < 8; ++jj) {
        int t = i + jj;
        int sl = r0 + ((t & 3) << 4) + (t >> 2);
        p[jj] = f2fp8(bf2f(E[sl * 129 + c]));
      }
      *(u8x8*)(dst + i) = p;
    }
  }
}

// =====================================================================
// MX-scaled fp8 pipelined 128x128 B^T GEMM (scores / PV), v2 layout.
// K-tile = 128 B stored as TWO r7-style halves of [128 rows][64B] (8KB
// each) -> row stride 64B so row parity reaches the bank index; frag
// read uses phys slot g ^ ((row>>1)&3), bijective in g per row ->
// 2 lanes/bank = conflict-free (r7-measured 0).  Lane g's 32 virtual-k
// bytes = [half0 chunk g] ++ [half1 chunk g]; A and B share the rule
// (dot-product invariant).  Staging: linear dest, inverse-permuted src.
// 512 thr, 8 waves (4M x 2N), per-wave 32x64. LDS 2 x 32KB = 64KB.
// mfma_scale_f32_16x16x128_f8f6f4 with unit E8M0 scales (exact 1.0).
// EPI: 6 scores  P(u8, kv-permuted packed u32) = exp(s*scale), rowsum L
//      7 PV      O = (P@V)/L -> oflat bf16 (packed u16x4, K-permuted)
// =====================================================================
template<int EPI>
__global__ __launch_bounds__(512, 4) void gemm_mx(
    const u8* __restrict__ A, const u8* __restrict__ B, void* __restrict__ Cv,
    float* __restrict__ Lbuf, int N, int K, float scale,
    long bsA, long bsB, long bsC)
{
  __shared__ alignas(16) char smem[65536];

  const int tid = threadIdx.x, lid = tid & 63, wid = tid >> 6;
  const int wm = wid >> 1, wn = wid & 1;     // 4 x 2 wave grid
  const int g = lid >> 4, r16 = lid & 15;

  const int nx = gridDim.x, ny = gridDim.y;
  const int lin = blockIdx.x + nx * (blockIdx.y + ny * blockIdx.z);
  const int xcd = lin & 7, slot = lin >> 3;
  const int wx = slot % nx;
  const int c_ = xcd + (slot / nx) * 8;
  const int m0 = (c_ % ny) * 128, n0 = wx * 128, z = c_ / ny;

  A += (size_t)z * bsA;
  B += (size_t)z * bsB;
  const int NT = K >> 7;   // K-tile = 128 bytes

  // frag byte offsets within a 32KB tile-buffer:
  // A half h at h*8192, B half h at 16384 + h*8192; 64B rows, slot g^swz(row)
  int offA[2], offB[4];
#pragma unroll
  for (int f = 0; f < 2; ++f) {
    int ra = wm * 32 + f * 16 + r16;
    offA[f] = ra * 64 + ((g ^ ((ra >> 1) & 3)) << 4);
  }
#pragma unroll
  for (int f = 0; f < 4; ++f) {
    int rb = wn * 64 + f * 16 + r16;
    offB[f] = rb * 64 + ((g ^ ((rb >> 1) & 3)) << 4);
  }

  auto stage_tile = [&](int ts) {
    char* base = smem + (ts & 1) * 32768;
    const u8* At = A + (size_t)ts * 128;
    const u8* Bt = B + (size_t)ts * 128;
    // A: 1024 chunks = half(2) x row(128) x physslot(4)
#pragma unroll
    for (int l = 0; l < 2; ++l) {
      int i = l * 512 + tid;
      int half = i >> 9, rem = i & 511, row = rem >> 2, x = rem & 3;
      int c = x ^ ((row >> 1) & 3);
      gld_lds16(At + (size_t)(m0 + row) * K + half * 64 + c * 16,
                base + half * 8192 + rem * 16);
    }
#pragma unroll
    for (int l = 0; l < 2; ++l) {
      int i = l * 512 + tid;
      int half = i >> 9, rem = i & 511, row = rem >> 2, x = rem & 3;
      int c = x ^ ((row >> 1) & 3);
      gld_lds16(Bt + (size_t)(n0 + row) * K + half * 64 + c * 16,
                base + 16384 + half * 8192 + rem * 16);
    }
  };

  f32x4 acc[2][4];
#pragma unroll
  for (int i = 0; i < 2; ++i)
#pragma unroll
    for (int j = 0; j < 4; ++j) acc[i][j] = 0.0f;

  stage_tile(0);
  stage_tile(1);
  asm volatile("s_waitcnt vmcnt(4)" ::: "memory");
  __builtin_amdgcn_s_barrier();

  for (int t = 0; t < NT; ++t) {
    const char* Ab = smem + (t & 1) * 32768;
    const char* Bb = Ab + 16384;
    i32x8 af[2], bfr[4];
#pragma unroll
    for (int f = 0; f < 2; ++f) {
      i32x4 lo = *(const i32x4*)(Ab + offA[f]);            // half 0
      i32x4 hi = *(const i32x4*)(Ab + 8192 + offA[f]);     // half 1
      af[f] = __builtin_shufflevector(lo, hi, 0, 1, 2, 3, 4, 5, 6, 7);
    }
#pragma unroll
    for (int f = 0; f < 4; ++f) {
      i32x4 lo = *(const i32x4*)(Bb + offB[f]);
      i32x4 hi = *(const i32x4*)(Bb + 8192 + offB[f]);
      bfr[f] = __builtin_shufflevector(lo, hi, 0, 1, 2, 3, 4, 5, 6, 7);
    }
    asm volatile("s_waitcnt lgkmcnt(0)" ::: "memory");
    __builtin_amdgcn_s_barrier();
    if (t + 2 < NT) stage_tile(t + 2);       // issue overlaps MFMA below
    __builtin_amdgcn_s_setprio(1);
#pragma unroll
    for (int mf = 0; mf < 2; ++mf)
#pragma unroll
      for (int nf = 0; nf < 4; ++nf)
        acc[mf][nf] = __builtin_amdgcn_mfma_scale_f32_16x16x128_f8f6f4(
            af[mf], bfr[nf], acc[mf][nf],
            0 /*cbsz: A=fp8*/, 0 /*blgp: B=fp8*/,
            0, 0x7F7F7F7F /*scaleA = 1.0*/, 0, 0x7F7F7F7F /*scaleB = 1.0*/);
    __builtin_amdgcn_s_setprio(0);
    if (t + 2 < NT) asm volatile("s_waitcnt vmcnt(4)" ::: "memory");
    else            asm volatile("s_waitcnt vmcnt(0)" ::: "memory");
    __builtin_amdgcn_s_barrier();
  }

  if constexpr (EPI == 6) {
    // P = exp(s*scale) -> fp8, kv-permuted packed u32; rowsum L via shfl+atomic
    u8* Cp = (u8*)Cv + (size_t)z * bsC;
    float* Lp = Lbuf + (size_t)z * 4096;
#pragma unroll
    for (int mf = 0; mf < 2; ++mf) {
#pragma unroll
      for (int r = 0; r < 4; ++r) {
        int gm = m0 + wm * 32 + mf * 16 + (g << 2) + r;
        float p0 = __expf(acc[mf][0][r] * scale);
        float p1 = __expf(acc[mf][1][r] * scale);
        float p2 = __expf(acc[mf][2][r] * scale);
        float p3 = __expf(acc[mf][3][r] * scale);
        float rs = (p0 + p1) + (p2 + p3);
        int pk = __builtin_amdgcn_cvt_pk_fp8_f32(p0, p1, 0, false);
        pk = __builtin_amdgcn_cvt_pk_fp8_f32(p2, p3, pk, true);
        *(u32*)(Cp + (size_t)gm * N + n0 + wn * 64 + r16 * 4) = (u32)pk;
        rs += __shfl_xor(rs, 1); rs += __shfl_xor(rs, 2);
        rs += __shfl_xor(rs, 4); rs += __shfl_xor(rs, 8);
        if (r16 == 0) atomicAdd(&Lp[gm], rs);
      }
    }
  } else {
    // PV: O = acc / L[row] -> oflat bf16, packed u16x4, cols within-64 permuted
    u16* C = (u16*)Cv + (size_t)z * bsC;
    const float* Lp = Lbuf + (size_t)z * 4096;
#pragma unroll
    for (int mf = 0; mf < 2; ++mf) {
#pragma unroll
      for (int r = 0; r < 4; ++r) {
        int gm = m0 + wm * 32 + mf * 16 + (g << 2) + r;
        float inv = 1.0f / Lp[gm];
        u16x4 o;
#pragma unroll
        for (int nf = 0; nf < 4; ++nf) o[nf] = f2bf(acc[mf][nf][r] * inv);
        *(u16x4*)(C + (size_t)(gm >> 3) * 4096 + (size_t)(gm & 7) * 512 +
                  n0 + wn * 64 + r16 * 4) = o;
      }
    }
  }
}

// ---------------- final projection, bf16 in, f32+bias out, 64x64 tile ----------------
__global__ __launch_bounds__(256) void gemm_bt_final(
    const u16* __restrict__ A, const u16* __restrict__ B, float* __restrict__ C,
    const float* __restrict__ bias, int N, int K)
{
  constexpr int BM = 64, BN = 64, BK = 64;
  __shared__ alignas(16) char smem[(BM + BN) * BK * 2];
  u16* As = (u16*)smem;
  u16* Bs = As + BM * BK;

  const int tid = threadIdx.x;
  const int lid = tid & 63, wid = tid >> 6;
  const int m0 = blockIdx.y * BM, n0 = blockIdx.x * BN;
  const int wm = wid >> 1, wn = wid & 1;

  f32x4 acc[2][2];
#pragma unroll
  for (int i = 0; i < 2; ++i)
#pragma unroll
    for (int j = 0; j < 2; ++j) acc[i][j] = 0.0f;

  const int rA = lid >> 3;
  const int ke = (lid & 7) * 8;

  const int nK = K / BK;
  for (int kt = 0; kt < nK; ++kt) {
    const int k0 = kt * BK;
#pragma unroll
    for (int c = 0; c < 2; ++c) {
      int chunk = wid * 2 + c;
      gld_lds16(A + (size_t)(m0 + chunk * 8 + rA) * K + k0 + ke, (char*)As + chunk * 1024);
    }
#pragma unroll
    for (int c = 0; c < 2; ++c) {
      int chunk = wid * 2 + c;
      gld_lds16(B + (size_t)(n0 + chunk * 8 + rA) * K + k0 + ke, (char*)Bs + chunk * 1024);
    }
    __syncthreads();
#pragma unroll
    for (int kc = 0; kc < 2; ++kc) {
      bf16x8 af[2], bfv[2];
      const int kb = kc * 32 + (lid >> 4) * 8;
#pragma unroll
      for (int i = 0; i < 2; ++i)
        af[i] = *(const bf16x8*)&As[(wm * 32 + i * 16 + (lid & 15)) * BK + kb];
#pragma unroll
      for (int j = 0; j < 2; ++j)
        bfv[j] = *(const bf16x8*)&Bs[(wn * 32 + j * 16 + (lid & 15)) * BK + kb];
#pragma unroll
      for (int i = 0; i < 2; ++i)
#pragma unroll
        for (int j = 0; j < 2; ++j)
          acc[i][j] = __builtin_amdgcn_mfma_f32_16x16x32_bf16(af[i], bfv[j], acc[i][j], 0, 0, 0);
    }
    __syncthreads();
  }

#pragma unroll
  for (int i = 0; i < 2; ++i)
#pragma unroll
    for (int j = 0; j < 2; ++j)
#pragma unroll
      for (int r = 0; r < 4; ++r) {
        int gm = m0 + wm * 32 + i * 16 + ((lid >> 4) << 2) + r;
        int gn = n0 + wn * 32 + j * 16 + (lid & 15);
        C[(size_t)gm * N + gn] = acc[i][j][r] + bias[gn];
      }
}

// ---------------------------------------------------------------------------
extern "C" void kernel_launch(void* const* d_in, const int* in_sizes, int n_in,
                              void* d_out, int out_size, void* d_ws, size_t ws_size,
                              hipStream_t stream) {
  (void)in_sizes; (void)n_in; (void)out_size; (void)ws_size;
  const float* q_f  = (const float*)d_in[0];
  const float* k_f  = (const float*)d_in[1];
  const float* v_f  = (const float*)d_in[2];
  const float* wq_b = (const float*)d_in[4];
  const float* wk_b = (const float*)d_in[6];
  const float* wv_b = (const float*)d_in[8];
  const float* ou_b = (const float*)d_in[10];
  float* out = (float*)d_out;

  char* ws = (char*)d_ws;
  u16* q_bf  = (u16*)(ws + 0);          // 2MB  bf16(q)
  u16* k_bf  = (u16*)(ws + 2097152);    // 2MB
  u16* v_bf  = (u16*)(ws + 4194304);    // 2MB
  u16* wA_q  = (u16*)(ws + 6291456);    // 4MB  bf16(wk_w) (reference swap)
  u16* wA_k  = (u16*)(ws + 10485760);   // 4MB  bf16(wq_w)
  u16* wA_v  = (u16*)(ws + 14680064);   // 4MB  bf16(wv_w)
  u16* ow_bf = (u16*)(ws + 18874368);   // 4MB  bf16(out_w), K within-64 permuted
  u8*  qp    = (u8*)(ws + 23068672);    // 8MB  (4,4096,512) fp8, l=s*8+h, d2 permuted
  u8*  kp    = (u8*)(ws + 31457280);    // 8MB  (4,4096,512) fp8, l'=h*512+s, d2 permuted
  u8*  vpt   = (u8*)(ws + 39845888);    // 8MB  (4,512,4096) fp8, [d2][kv-permuted]
  u16* oflat = (u16*)(ws + 48234496);   // 16MB (4,512,4096) bf16, cols within-64 permuted
  u8*  P     = (u8*)(ws + 65011712);    // 64MB (4,4096,4096) fp8, cols kv-permuted

  float* L = (float*)d_out;  // 64KB row-sums; dead until final GEMM overwrites

  // all converts in one launch
  cvt_all<<<5632, 256, 0, stream>>>(
      q_f, k_f, v_f, (const float*)d_in[5], (const float*)d_in[3],
      (const float*)d_in[7], (const float*)d_in[9],
      q_bf, k_bf, v_bf, wA_q, wA_k, wA_v, ow_bf);

  // all three projections in one launch (reference swap: qp uses wk, kp uses wq)
  gemm_proj<<<dim3(32,16,3), 256, 0, stream>>>(
      q_bf, k_bf, v_bf, wA_q, wA_k, wA_v, qp, kp, vpt, wk_b, wq_b, wv_b, 4096, 512);

  const float scl = 0.04419417382415922f;  // 1/sqrt(512)
  hipMemsetAsync(L, 0, 65536, stream);
  // scores: P = exp(s*scl) fp8 (kv-permuted) + row-sums into L  (MX fp8, K=128)
  gemm_mx<6><<<dim3(32,32,4), 512, 0, stream>>>(qp, kp, P, L, 4096, 512, scl,
                                                2097152, 2097152, 16777216);
  // PV: O = (P @ V) / L -> oflat bf16  (MX fp8, K=128, NT=32)
  gemm_mx<7><<<dim3(4,32,4), 512, 0, stream>>>(P, vpt, oflat, L, 512, 4096, 1.f,
                                               16777216, 2097152, 2097152);
  // final projection, bf16 -> f32 + bias (oflat & ow_bf share the K permutation)
  gemm_bt_final<<<dim3(8,32,1), 256, 0, stream>>>(oflat, ow_bf, out, ou_b, 512, 4096);
}

// Round 15
// 206.202 us; speedup vs baseline: 1.1363x; 1.1005x over previous
//
#include <hip/hip_runtime.h>
#include <cstddef>

typedef unsigned short u16;
typedef unsigned char u8;
typedef unsigned u32;
typedef float f32x4 __attribute__((ext_vector_type(4)));
typedef u16 u16x4 __attribute__((ext_vector_type(4)));
typedef u16 u16x8 __attribute__((ext_vector_type(8)));
typedef u8 u8x8 __attribute__((ext_vector_type(8)));
typedef __bf16 bf16x8 __attribute__((ext_vector_type(8)));
typedef int i32x4 __attribute__((ext_vector_type(4)));
typedef int i32x8 __attribute__((ext_vector_type(8)));
typedef long lx2 __attribute__((ext_vector_type(2)));

__device__ __forceinline__ u16 f2bf(float f) {
  u32 u = __builtin_bit_cast(u32, f);
  u += 0x7fffu + ((u >> 16) & 1u);   // RTNE
  return (u16)(u >> 16);
}
__device__ __forceinline__ float bf2f(u16 h) {
  return __builtin_bit_cast(float, ((u32)h) << 16);
}
__device__ __forceinline__ u8 f2fp8(float v) {
  int t = __builtin_amdgcn_cvt_pk_fp8_f32(v, v, 0, false);
  return (u8)(t & 0xff);
}
__device__ __forceinline__ void gld_lds16(const void* g, void* l) {
  __builtin_amdgcn_global_load_lds((const __attribute__((address_space(1))) void*)g,
                                   (__attribute__((address_space(3))) void*)l, 16, 0, 0);
}

// ---------------- all f32->bf16 converts in ONE launch ----------------
__global__ __launch_bounds__(256) void cvt_all(
    const float* __restrict__ q, const float* __restrict__ k, const float* __restrict__ v,
    const float* __restrict__ w5, const float* __restrict__ w3,
    const float* __restrict__ w7, const float* __restrict__ w9,
    u16* __restrict__ o_q, u16* __restrict__ o_k, u16* __restrict__ o_v,
    u16* __restrict__ o_wq, u16* __restrict__ o_wk, u16* __restrict__ o_wv,
    u16* __restrict__ o_ow)
{
  int b = blockIdx.x;
  const float* in; u16* out; int base; bool perm = false;
  if      (b < 512)  { in = q;  out = o_q;  base = b; }
  else if (b < 1024) { in = k;  out = o_k;  base = b - 512; }
  else if (b < 1536) { in = v;  out = o_v;  base = b - 1024; }
  else if (b < 2560) { in = w5; out = o_wq; base = b - 1536; }
  else if (b < 3584) { in = w3; out = o_wk; base = b - 2560; }
  else if (b < 4608) { in = w7; out = o_wv; base = b - 3584; }
  else               { in = w9; out = o_ow; base = b - 4608; perm = true; }
  int i = (base * 256 + threadIdx.x) * 8;
  u16x8 o;
  if (!perm) {
    f32x4 a = *(const f32x4*)(in + i);
    f32x4 c = *(const f32x4*)(in + i + 4);
    o[0] = f2bf(a[0]); o[1] = f2bf(a[1]); o[2] = f2bf(a[2]); o[3] = f2bf(a[3]);
    o[4] = f2bf(c[0]); o[5] = f2bf(c[1]); o[6] = f2bf(c[2]); o[7] = f2bf(c[3]);
  } else {
    // within-64 K-group permutation: pos t <- true (t&3)*16+(t>>2)
    int row = i >> 12, col0 = i & 4095;
    int group = col0 & ~63, t0 = col0 & 63;
    const float* rp = in + ((size_t)row << 12) + group;
#pragma unroll
    for (int j = 0; j < 8; ++j) {
      int t = t0 + j;
      o[j] = f2bf(rp[((t & 3) << 4) + (t >> 2)]);
    }
  }
  *(u16x8*)(out + i) = o;
}

// =====================================================================
// bf16 pipelined 128x128 B^T GEMM — ALL THREE projections, one launch.
// (unchanged — passing, issue-early staging, K-tile 32)
// =====================================================================
__global__ __launch_bounds__(256, 2) void gemm_proj(
    const u16* __restrict__ Aq, const u16* __restrict__ Ak, const u16* __restrict__ Av,
    const u16* __restrict__ Bq, const u16* __restrict__ Bk, const u16* __restrict__ Bv,
    u8* __restrict__ Cq, u8* __restrict__ Ck, u8* __restrict__ Cvv,
    const float* __restrict__ bq, const float* __restrict__ bk, const float* __restrict__ bv,
    int N, int K)
{
  __shared__ alignas(16) char smem[33024];

  const int tid = threadIdx.x, lid = tid & 63, wid = tid >> 6;
  const int wm = wid >> 1, wn = wid & 1;
  const int g = lid >> 4, r16 = lid & 15;
  const int which = blockIdx.z;

  const u16* A = (which == 0) ? Aq : (which == 1) ? Ak : Av;
  const u16* B = (which == 0) ? Bq : (which == 1) ? Bk : Bv;
  u8* C = (which == 0) ? Cq : (which == 1) ? Ck : Cvv;
  const float* bias = (which == 0) ? bq : (which == 1) ? bk : bv;

  const int nx = gridDim.x, ny = gridDim.y;
  const int lin = blockIdx.x + nx * blockIdx.y;
  const int xcd = lin & 7, slot = lin >> 3;
  const int wx = slot % nx;
  const int c_ = xcd + (slot / nx) * 8;
  const int m0 = (c_ % ny) * 128, n0 = wx * 128;

  const int NT = K >> 5;

  int offA[4], offB[4];
#pragma unroll
  for (int f = 0; f < 4; ++f) {
    int ra = wm * 64 + f * 16 + r16;
    offA[f] = ra * 64 + ((g ^ ((ra >> 1) & 3)) << 4);
    int rb = wn * 64 + f * 16 + r16;
    offB[f] = rb * 64 + ((g ^ ((rb >> 1) & 3)) << 4);
  }

  auto stage_tile = [&](int ts) {
    char* base = smem + (ts & 1) * 16384;
    const u16* At = A + (size_t)ts * 32;
    const u16* Bt = B + (size_t)ts * 32;
#pragma unroll
    for (int l = 0; l < 2; ++l) {
      int i = l * 256 + tid;
      int row = i >> 2, x = i & 3;
      int c = x ^ ((row >> 1) & 3);
      gld_lds16(At + (size_t)(m0 + row) * K + c * 8, base + i * 16);
    }
#pragma unroll
    for (int l = 0; l < 2; ++l) {
      int i = l * 256 + tid;
      int row = i >> 2, x = i & 3;
      int c = x ^ ((row >> 1) & 3);
      gld_lds16(Bt + (size_t)(n0 + row) * K + c * 8, base + 8192 + i * 16);
    }
  };

  f32x4 acc[4][4];
#pragma unroll
  for (int i = 0; i < 4; ++i)
#pragma unroll
    for (int j = 0; j < 4; ++j) acc[i][j] = 0.0f;

  stage_tile(0);
  stage_tile(1);
  asm volatile("s_waitcnt vmcnt(4)" ::: "memory");
  __builtin_amdgcn_s_barrier();

  for (int t = 0; t < NT; ++t) {
    const char* Ab = smem + (t & 1) * 16384;
    const char* Bb = Ab + 8192;
    bf16x8 ar[4], br[4];
#pragma unroll
    for (int f = 0; f < 4; ++f) ar[f] = *(const bf16x8*)(Ab + offA[f]);
#pragma unroll
    for (int f = 0; f < 4; ++f) br[f] = *(const bf16x8*)(Bb + offB[f]);
    asm volatile("s_waitcnt lgkmcnt(0)" ::: "memory");
    __builtin_amdgcn_s_barrier();
    if (t + 2 < NT) stage_tile(t + 2);
    __builtin_amdgcn_s_setprio(1);
#pragma unroll
    for (int mf = 0; mf < 4; ++mf)
#pragma unroll
      for (int nf = 0; nf < 4; ++nf)
        acc[mf][nf] = __builtin_amdgcn_mfma_f32_16x16x32_bf16(ar[mf], br[nf], acc[mf][nf], 0, 0, 0);
    __builtin_amdgcn_s_setprio(0);
    if (t + 2 < NT) asm volatile("s_waitcnt vmcnt(4)" ::: "memory");
    else            asm volatile("s_waitcnt vmcnt(0)" ::: "memory");
    __builtin_amdgcn_s_barrier();
  }

  if (which < 2) {
    const int hh = (n0 + wn * 64) >> 9;
    const int d2g = (n0 & 511) + wn * 64;
#pragma unroll
    for (int mf = 0; mf < 4; ++mf)
#pragma unroll
      for (int r = 0; r < 4; ++r) {
        int gm = m0 + wm * 64 + mf * 16 + (g << 2) + r;
        int b = gm >> 9, s = gm & 511;
        float v0 = acc[mf][0][r] + bias[n0 + wn * 64 + 0 * 16 + r16];
        float v1 = acc[mf][1][r] + bias[n0 + wn * 64 + 1 * 16 + r16];
        float v2 = acc[mf][2][r] + bias[n0 + wn * 64 + 2 * 16 + r16];
        float v3 = acc[mf][3][r] + bias[n0 + wn * 64 + 3 * 16 + r16];
        int pk = __builtin_amdgcn_cvt_pk_fp8_f32(v0, v1, 0, false);
        pk = __builtin_amdgcn_cvt_pk_fp8_f32(v2, v3, pk, true);
        int row = (which == 0) ? ((s << 3) + hh) : ((hh << 9) + s);
        *(u32*)(C + (size_t)b * 2097152 + (size_t)row * 512 + d2g + r16 * 4) = (u32)pk;
      }
  } else {
    u16* E = (u16*)smem;   // 128 x 129 bf16
#pragma unroll
    for (int mf = 0; mf < 4; ++mf)
#pragma unroll
      for (int nf = 0; nf < 4; ++nf)
#pragma unroll
        for (int r = 0; r < 4; ++r) {
          int lm = wm * 64 + mf * 16 + (g << 2) + r;
          int ln = wn * 64 + nf * 16 + r16;
          E[lm * 129 + ln] = f2bf(acc[mf][nf][r] + bias[n0 + ln]);
        }
    __syncthreads();
    int b = m0 >> 9, s0 = m0 & 511, hh = n0 >> 9, d20 = n0 & 511;
    int c = tid >> 1;
    int r0 = (tid & 1) * 64;
    u8* dst = C + (size_t)b * 2097152 + (size_t)(d20 + c) * 4096 + (hh << 9) + s0 + r0;
#pragma unroll
    for (int i = 0; i < 64; i += 8) {
      u8x8 p;
#pragma unroll
      for (int jj = 0; jj < 8; ++jj) {
        int t = i + jj;
        int sl = r0 + ((t & 3) << 4) + (t >> 2);
        p[jj] = f2fp8(bf2f(E[sl * 129 + c]));
      }
      *(u8x8*)(dst + i) = p;
    }
  }
}

// =====================================================================
// fp8 pipelined 128x128 B^T GEMM — SCORES (round-12 proven: 74 µs,
// MfmaUtil 38%, 0 conflicts).  256 thr, 4 waves, K-tile 64B, NT=8.
// EPI 6: P = exp(s*scale) fp8 (kv-permuted packed u32) + rowsum L.
// =====================================================================
__global__ __launch_bounds__(256, 4) void gemm_f8s(
    const u8* __restrict__ A, const u8* __restrict__ B, u8* __restrict__ Cv,
    float* __restrict__ Lbuf, int N, int K, float scale,
    long bsA, long bsB, long bsC)
{
  constexpr int SLOT = 256 * 64;
  __shared__ alignas(16) char smem[2 * SLOT];

  const int tid = threadIdx.x, lid = tid & 63, wid = tid >> 6;
  const int wm = wid >> 1, wn = wid & 1;
  const int g = lid >> 4, r16 = lid & 15;

  const int nx = gridDim.x, ny = gridDim.y;
  const int lin = blockIdx.x + nx * (blockIdx.y + ny * blockIdx.z);
  const int xcd = lin & 7, slot = lin >> 3;
  const int wx = slot % nx;
  const int c_ = xcd + (slot / nx) * 8;
  const int m0 = (c_ % ny) * 128, n0 = wx * 128, z = c_ / ny;

  A += (size_t)z * bsA;
  B += (size_t)z * bsB;
  const int NT = K >> 6;

  int offA[4], offB[4];
#pragma unroll
  for (int f = 0; f < 4; ++f) {
    int ra = wm * 64 + f * 16 + r16;
    offA[f] = ra * 64 + ((g ^ ((ra >> 1) & 3)) << 4);
    int rb = wn * 64 + f * 16 + r16;
    offB[f] = rb * 64 + ((g ^ ((rb >> 1) & 3)) << 4);
  }

  auto stage_tile = [&](int ts) {
    char* base = smem + (ts & 1) * SLOT;
    const u8* At = A + (size_t)ts * 64;
    const u8* Bt = B + (size_t)ts * 64;
#pragma unroll
    for (int l = 0; l < 2; ++l) {
      int i = l * 256 + tid;
      int row = i >> 2, x = i & 3;
      int c = x ^ ((row >> 1) & 3);
      gld_lds16(At + (size_t)(m0 + row) * K + c * 16, base + i * 16);
    }
#pragma unroll
    for (int l = 0; l < 2; ++l) {
      int i = l * 256 + tid;
      int row = i >> 2, x = i & 3;
      int c = x ^ ((row >> 1) & 3);
      gld_lds16(Bt + (size_t)(n0 + row) * K + c * 16, base + 8192 + i * 16);
    }
  };

  f32x4 acc[4][4];
#pragma unroll
  for (int i = 0; i < 4; ++i)
#pragma unroll
    for (int j = 0; j < 4; ++j) acc[i][j] = 0.0f;

  stage_tile(0);
  stage_tile(1);
  asm volatile("s_waitcnt vmcnt(4)" ::: "memory");
  __builtin_amdgcn_s_barrier();

  for (int t = 0; t < NT; ++t) {
    const char* Ab = smem + (t & 1) * SLOT;
    const char* Bb = Ab + 8192;
    lx2 ar[4], br[4];
#pragma unroll
    for (int f = 0; f < 4; ++f) ar[f] = *(const lx2*)(Ab + offA[f]);
#pragma unroll
    for (int f = 0; f < 4; ++f) br[f] = *(const lx2*)(Bb + offB[f]);
    asm volatile("s_waitcnt lgkmcnt(0)" ::: "memory");
    __builtin_amdgcn_s_barrier();
    if (t + 2 < NT) stage_tile(t + 2);          // issue overlaps MFMA below
    __builtin_amdgcn_s_setprio(1);
#pragma unroll
    for (int mf = 0; mf < 4; ++mf)
#pragma unroll
      for (int nf = 0; nf < 4; ++nf) {
        acc[mf][nf] = __builtin_amdgcn_mfma_f32_16x16x32_fp8_fp8(ar[mf][0], br[nf][0], acc[mf][nf], 0, 0, 0);
        acc[mf][nf] = __builtin_amdgcn_mfma_f32_16x16x32_fp8_fp8(ar[mf][1], br[nf][1], acc[mf][nf], 0, 0, 0);
      }
    __builtin_amdgcn_s_setprio(0);
    if (t + 2 < NT) asm volatile("s_waitcnt vmcnt(4)" ::: "memory");
    else            asm volatile("s_waitcnt vmcnt(0)" ::: "memory");
    __builtin_amdgcn_s_barrier();
  }

  // P = exp(s*scale) -> fp8, kv-permuted packed u32; rowsum L via shfl+atomic
  u8* Cp = Cv + (size_t)z * bsC;
  float* Lp = Lbuf + (size_t)z * 4096;
#pragma unroll
  for (int mf = 0; mf < 4; ++mf) {
#pragma unroll
    for (int r = 0; r < 4; ++r) {
      int gm = m0 + wm * 64 + mf * 16 + (g << 2) + r;
      float p0 = __expf(acc[mf][0][r] * scale);
      float p1 = __expf(acc[mf][1][r] * scale);
      float p2 = __expf(acc[mf][2][r] * scale);
      float p3 = __expf(acc[mf][3][r] * scale);
      float rs = (p0 + p1) + (p2 + p3);
      int pk = __builtin_amdgcn_cvt_pk_fp8_f32(p0, p1, 0, false);
      pk = __builtin_amdgcn_cvt_pk_fp8_f32(p2, p3, pk, true);
      *(u32*)(Cp + (size_t)gm * N + n0 + wn * 64 + r16 * 4) = (u32)pk;
      rs += __shfl_xor(rs, 1); rs += __shfl_xor(rs, 2);
      rs += __shfl_xor(rs, 4); rs += __shfl_xor(rs, 8);
      if (r16 == 0) atomicAdd(&Lp[gm], rs);
    }
  }
}

// =====================================================================
// MX-scaled fp8 pipelined 128x128 B^T GEMM — PV (round-14 proven, ~30 µs).
// K-tile 128B as two r7-style 64B-row halves; conflict-free.  NT=K/128=32.
// 512 thr, 8 waves (4M x 2N); mfma_scale 16x16x128, unit E8M0 scales.
// EPI 7: O = (P@V)/L -> oflat bf16 (packed u16x4, K-permuted).
// =====================================================================
__global__ __launch_bounds__(512, 4) void gemm_mx_pv(
    const u8* __restrict__ A, const u8* __restrict__ B, u16* __restrict__ Cv,
    const float* __restrict__ Lbuf, int N, int K,
    long bsA, long bsB, long bsC)
{
  __shared__ alignas(16) char smem[65536];

  const int tid = threadIdx.x, lid = tid & 63, wid = tid >> 6;
  const int wm = wid >> 1, wn = wid & 1;     // 4 x 2 wave grid
  const int g = lid >> 4, r16 = lid & 15;

  const int nx = gridDim.x, ny = gridDim.y;
  const int lin = blockIdx.x + nx * (blockIdx.y + ny * blockIdx.z);
  const int xcd = lin & 7, slot = lin >> 3;
  const int wx = slot % nx;
  const int c_ = xcd + (slot / nx) * 8;
  const int m0 = (c_ % ny) * 128, n0 = wx * 128, z = c_ / ny;

  A += (size_t)z * bsA;
  B += (size_t)z * bsB;
  const int NT = K >> 7;   // K-tile = 128 bytes

  int offA[2], offB[4];
#pragma unroll
  for (int f = 0; f < 2; ++f) {
    int ra = wm * 32 + f * 16 + r16;
    offA[f] = ra * 64 + ((g ^ ((ra >> 1) & 3)) << 4);
  }
#pragma unroll
  for (int f = 0; f < 4; ++f) {
    int rb = wn * 64 + f * 16 + r16;
    offB[f] = rb * 64 + ((g ^ ((rb >> 1) & 3)) << 4);
  }

  auto stage_tile = [&](int ts) {
    char* base = smem + (ts & 1) * 32768;
    const u8* At = A + (size_t)ts * 128;
    const u8* Bt = B + (size_t)ts * 128;
#pragma unroll
    for (int l = 0; l < 2; ++l) {
      int i = l * 512 + tid;
      int half = i >> 9, rem = i & 511, row = rem >> 2, x = rem & 3;
      int c = x ^ ((row >> 1) & 3);
      gld_lds16(At + (size_t)(m0 + row) * K + half * 64 + c * 16,
                base + half * 8192 + rem * 16);
    }
#pragma unroll
    for (int l = 0; l < 2; ++l) {
      int i = l * 512 + tid;
      int half = i >> 9, rem = i & 511, row = rem >> 2, x = rem & 3;
      int c = x ^ ((row >> 1) & 3);
      gld_lds16(Bt + (size_t)(n0 + row) * K + half * 64 + c * 16,
                base + 16384 + half * 8192 + rem * 16);
    }
  };

  f32x4 acc[2][4];
#pragma unroll
  for (int i = 0; i < 2; ++i)
#pragma unroll
    for (int j = 0; j < 4; ++j) acc[i][j] = 0.0f;

  stage_tile(0);
  stage_tile(1);
  asm volatile("s_waitcnt vmcnt(4)" ::: "memory");
  __builtin_amdgcn_s_barrier();

  for (int t = 0; t < NT; ++t) {
    const char* Ab = smem + (t & 1) * 32768;
    const char* Bb = Ab + 16384;
    i32x8 af[2], bfr[4];
#pragma unroll
    for (int f = 0; f < 2; ++f) {
      i32x4 lo = *(const i32x4*)(Ab + offA[f]);            // half 0
      i32x4 hi = *(const i32x4*)(Ab + 8192 + offA[f]);     // half 1
      af[f] = __builtin_shufflevector(lo, hi, 0, 1, 2, 3, 4, 5, 6, 7);
    }
#pragma unroll
    for (int f = 0; f < 4; ++f) {
      i32x4 lo = *(const i32x4*)(Bb + offB[f]);
      i32x4 hi = *(const i32x4*)(Bb + 8192 + offB[f]);
      bfr[f] = __builtin_shufflevector(lo, hi, 0, 1, 2, 3, 4, 5, 6, 7);
    }
    asm volatile("s_waitcnt lgkmcnt(0)" ::: "memory");
    __builtin_amdgcn_s_barrier();
    if (t + 2 < NT) stage_tile(t + 2);       // issue overlaps MFMA below
    __builtin_amdgcn_s_setprio(1);
#pragma unroll
    for (int mf = 0; mf < 2; ++mf)
#pragma unroll
      for (int nf = 0; nf < 4; ++nf)
        acc[mf][nf] = __builtin_amdgcn_mfma_scale_f32_16x16x128_f8f6f4(
            af[mf], bfr[nf], acc[mf][nf],
            0 /*cbsz: A=fp8*/, 0 /*blgp: B=fp8*/,
            0, 0x7F7F7F7F /*scaleA = 1.0*/, 0, 0x7F7F7F7F /*scaleB = 1.0*/);
    __builtin_amdgcn_s_setprio(0);
    if (t + 2 < NT) asm volatile("s_waitcnt vmcnt(4)" ::: "memory");
    else            asm volatile("s_waitcnt vmcnt(0)" ::: "memory");
    __builtin_amdgcn_s_barrier();
  }

  // PV: O = acc / L[row] -> oflat bf16, packed u16x4, cols within-64 permuted
  u16* C = Cv + (size_t)z * bsC;
  const float* Lp = Lbuf + (size_t)z * 4096;
#pragma unroll
  for (int mf = 0; mf < 2; ++mf) {
#pragma unroll
    for (int r = 0; r < 4; ++r) {
      int gm = m0 + wm * 32 + mf * 16 + (g << 2) + r;
      float inv = 1.0f / Lp[gm];
      u16x4 o;
#pragma unroll
      for (int nf = 0; nf < 4; ++nf) o[nf] = f2bf(acc[mf][nf][r] * inv);
      *(u16x4*)(C + (size_t)(gm >> 3) * 4096 + (size_t)(gm & 7) * 512 +
                n0 + wn * 64 + r16 * 4) = o;
    }
  }
}

// ---------------- final projection, bf16 in, f32+bias out, 64x64 tile ----------------
__global__ __launch_bounds__(256) void gemm_bt_final(
    const u16* __restrict__ A, const u16* __restrict__ B, float* __restrict__ C,
    const float* __restrict__ bias, int N, int K)
{
  constexpr int BM = 64, BN = 64, BK = 64;
  __shared__ alignas(16) char smem[(BM + BN) * BK * 2];
  u16* As = (u16*)smem;
  u16* Bs = As + BM * BK;

  const int tid = threadIdx.x;
  const int lid = tid & 63, wid = tid >> 6;
  const int m0 = blockIdx.y * BM, n0 = blockIdx.x * BN;
  const int wm = wid >> 1, wn = wid & 1;

  f32x4 acc[2][2];
#pragma unroll
  for (int i = 0; i < 2; ++i)
#pragma unroll
    for (int j = 0; j < 2; ++j) acc[i][j] = 0.0f;

  const int rA = lid >> 3;
  const int ke = (lid & 7) * 8;

  const int nK = K / BK;
  for (int kt = 0; kt < nK; ++kt) {
    const int k0 = kt * BK;
#pragma unroll
    for (int c = 0; c < 2; ++c) {
      int chunk = wid * 2 + c;
      gld_lds16(A + (size_t)(m0 + chunk * 8 + rA) * K + k0 + ke, (char*)As + chunk * 1024);
    }
#pragma unroll
    for (int c = 0; c < 2; ++c) {
      int chunk = wid * 2 + c;
      gld_lds16(B + (size_t)(n0 + chunk * 8 + rA) * K + k0 + ke, (char*)Bs + chunk * 1024);
    }
    __syncthreads();
#pragma unroll
    for (int kc = 0; kc < 2; ++kc) {
      bf16x8 af[2], bfv[2];
      const int kb = kc * 32 + (lid >> 4) * 8;
#pragma unroll
      for (int i = 0; i < 2; ++i)
        af[i] = *(const bf16x8*)&As[(wm * 32 + i * 16 + (lid & 15)) * BK + kb];
#pragma unroll
      for (int j = 0; j < 2; ++j)
        bfv[j] = *(const bf16x8*)&Bs[(wn * 32 + j * 16 + (lid & 15)) * BK + kb];
#pragma unroll
      for (int i = 0; i < 2; ++i)
#pragma unroll
        for (int j = 0; j < 2; ++j)
          acc[i][j] = __builtin_amdgcn_mfma_f32_16x16x32_bf16(af[i], bfv[j], acc[i][j], 0, 0, 0);
    }
    __syncthreads();
  }

#pragma unroll
  for (int i = 0; i < 2; ++i)
#pragma unroll
    for (int j = 0; j < 2; ++j)
#pragma unroll
      for (int r = 0; r < 4; ++r) {
        int gm = m0 + wm * 32 + i * 16 + ((lid >> 4) << 2) + r;
        int gn = n0 + wn * 32 + j * 16 + (lid & 15);
        C[(size_t)gm * N + gn] = acc[i][j][r] + bias[gn];
      }
}

// ---------------------------------------------------------------------------
extern "C" void kernel_launch(void* const* d_in, const int* in_sizes, int n_in,
                              void* d_out, int out_size, void* d_ws, size_t ws_size,
                              hipStream_t stream) {
  (void)in_sizes; (void)n_in; (void)out_size; (void)ws_size;
  const float* q_f  = (const float*)d_in[0];
  const float* k_f  = (const float*)d_in[1];
  const float* v_f  = (const float*)d_in[2];
  const float* wq_b = (const float*)d_in[4];
  const float* wk_b = (const float*)d_in[6];
  const float* wv_b = (const float*)d_in[8];
  const float* ou_b = (const float*)d_in[10];
  float* out = (float*)d_out;

  char* ws = (char*)d_ws;
  u16* q_bf  = (u16*)(ws + 0);          // 2MB  bf16(q)
  u16* k_bf  = (u16*)(ws + 2097152);    // 2MB
  u16* v_bf  = (u16*)(ws + 4194304);    // 2MB
  u16* wA_q  = (u16*)(ws + 6291456);    // 4MB  bf16(wk_w) (reference swap)
  u16* wA_k  = (u16*)(ws + 10485760);   // 4MB  bf16(wq_w)
  u16* wA_v  = (u16*)(ws + 14680064);   // 4MB  bf16(wv_w)
  u16* ow_bf = (u16*)(ws + 18874368);   // 4MB  bf16(out_w), K within-64 permuted
  u8*  qp    = (u8*)(ws + 23068672);    // 8MB  (4,4096,512) fp8, l=s*8+h, d2 permuted
  u8*  kp    = (u8*)(ws + 31457280);    // 8MB  (4,4096,512) fp8, l'=h*512+s, d2 permuted
  u8*  vpt   = (u8*)(ws + 39845888);    // 8MB  (4,512,4096) fp8, [d2][kv-permuted]
  u16* oflat = (u16*)(ws + 48234496);   // 16MB (4,512,4096) bf16, cols within-64 permuted
  u8*  P     = (u8*)(ws + 65011712);    // 64MB (4,4096,4096) fp8, cols kv-permuted

  float* L = (float*)d_out;  // 64KB row-sums; dead until final GEMM overwrites

  // all converts in one launch
  cvt_all<<<5632, 256, 0, stream>>>(
      q_f, k_f, v_f, (const float*)d_in[5], (const float*)d_in[3],
      (const float*)d_in[7], (const float*)d_in[9],
      q_bf, k_bf, v_bf, wA_q, wA_k, wA_v, ow_bf);

  // all three projections in one launch (reference swap: qp uses wk, kp uses wq)
  gemm_proj<<<dim3(32,16,3), 256, 0, stream>>>(
      q_bf, k_bf, v_bf, wA_q, wA_k, wA_v, qp, kp, vpt, wk_b, wq_b, wv_b, 4096, 512);

  const float scl = 0.04419417382415922f;  // 1/sqrt(512)
  hipMemsetAsync(L, 0, 65536, stream);
  // scores: P = exp(s*scl) fp8 (kv-permuted) + row-sums into L  (fp8, NT=8)
  gemm_f8s<<<dim3(32,32,4), 256, 0, stream>>>(qp, kp, P, L, 4096, 512, scl,
                                              2097152, 2097152, 16777216);
  // PV: O = (P @ V) / L -> oflat bf16  (MX fp8, K=128, NT=32)
  gemm_mx_pv<<<dim3(4,32,4), 512, 0, stream>>>(P, vpt, oflat, L, 512, 4096,
                                               16777216, 2097152, 2097152);
  // final projection, bf16 -> f32 + bias (oflat & ow_bf share the K permutation)
  gemm_bt_final<<<dim3(8,32,1), 256, 0, stream>>>(oflat, ow_bf, out, ou_b, 512, 4096);
}

// Round 16
// 178.294 us; speedup vs baseline: 1.3142x; 1.1565x over previous
//
#include <hip/hip_runtime.h>
#include <cstddef>

typedef unsigned short u16;
typedef unsigned char u8;
typedef unsigned u32;
typedef float f32x4 __attribute__((ext_vector_type(4)));
typedef u16 u16x4 __attribute__((ext_vector_type(4)));
typedef u16 u16x8 __attribute__((ext_vector_type(8)));
typedef u8 u8x8 __attribute__((ext_vector_type(8)));
typedef __bf16 bf16x8 __attribute__((ext_vector_type(8)));
typedef int i32x4 __attribute__((ext_vector_type(4)));
typedef int i32x8 __attribute__((ext_vector_type(8)));
typedef long lx2 __attribute__((ext_vector_type(2)));

__device__ __forceinline__ u16 f2bf(float f) {
  u32 u = __builtin_bit_cast(u32, f);
  u += 0x7fffu + ((u >> 16) & 1u);   // RTNE
  return (u16)(u >> 16);
}
__device__ __forceinline__ float bf2f(u16 h) {
  return __builtin_bit_cast(float, ((u32)h) << 16);
}
__device__ __forceinline__ u8 f2fp8(float v) {
  int t = __builtin_amdgcn_cvt_pk_fp8_f32(v, v, 0, false);
  return (u8)(t & 0xff);
}
__device__ __forceinline__ void gld_lds16(const void* g, void* l) {
  __builtin_amdgcn_global_load_lds((const __attribute__((address_space(1))) void*)g,
                                   (__attribute__((address_space(3))) void*)l, 16, 0, 0);
}

// ---------------- all f32->bf16 converts + L-zero in ONE launch ----------------
__global__ __launch_bounds__(256) void cvt_all(
    const float* __restrict__ q, const float* __restrict__ k, const float* __restrict__ v,
    const float* __restrict__ w5, const float* __restrict__ w3,
    const float* __restrict__ w7, const float* __restrict__ w9,
    u16* __restrict__ o_q, u16* __restrict__ o_k, u16* __restrict__ o_v,
    u16* __restrict__ o_wq, u16* __restrict__ o_wk, u16* __restrict__ o_wv,
    u16* __restrict__ o_ow, float* __restrict__ Lz)
{
  int b = blockIdx.x;
  if (b >= 5632) {                     // zero the 16384-float L buffer
    f32x4 z4 = 0.0f;
    float* p = Lz + threadIdx.x * 64;
#pragma unroll
    for (int j = 0; j < 16; ++j) *(f32x4*)(p + j * 4) = z4;
    return;
  }
  const float* in; u16* out; int base; bool perm = false;
  if      (b < 512)  { in = q;  out = o_q;  base = b; }
  else if (b < 1024) { in = k;  out = o_k;  base = b - 512; }
  else if (b < 1536) { in = v;  out = o_v;  base = b - 1024; }
  else if (b < 2560) { in = w5; out = o_wq; base = b - 1536; }
  else if (b < 3584) { in = w3; out = o_wk; base = b - 2560; }
  else if (b < 4608) { in = w7; out = o_wv; base = b - 3584; }
  else               { in = w9; out = o_ow; base = b - 4608; perm = true; }
  int i = (base * 256 + threadIdx.x) * 8;
  u16x8 o;
  if (!perm) {
    f32x4 a = *(const f32x4*)(in + i);
    f32x4 c = *(const f32x4*)(in + i + 4);
    o[0] = f2bf(a[0]); o[1] = f2bf(a[1]); o[2] = f2bf(a[2]); o[3] = f2bf(a[3]);
    o[4] = f2bf(c[0]); o[5] = f2bf(c[1]); o[6] = f2bf(c[2]); o[7] = f2bf(c[3]);
  } else {
    // within-64 K-group permutation: pos t <- true (t&3)*16+(t>>2)
    int row = i >> 12, col0 = i & 4095;
    int group = col0 & ~63, t0 = col0 & 63;
    const float* rp = in + ((size_t)row << 12) + group;
#pragma unroll
    for (int j = 0; j < 8; ++j) {
      int t = t0 + j;
      o[j] = f2bf(rp[((t & 3) << 4) + (t >> 2)]);
    }
  }
  *(u16x8*)(out + i) = o;
}

// =====================================================================
// bf16 pipelined 128x128 B^T GEMM — ALL THREE projections, one launch.
// (unchanged — passing, issue-early staging, K-tile 32)
// =====================================================================
__global__ __launch_bounds__(256, 2) void gemm_proj(
    const u16* __restrict__ Aq, const u16* __restrict__ Ak, const u16* __restrict__ Av,
    const u16* __restrict__ Bq, const u16* __restrict__ Bk, const u16* __restrict__ Bv,
    u8* __restrict__ Cq, u8* __restrict__ Ck, u8* __restrict__ Cvv,
    const float* __restrict__ bq, const float* __restrict__ bk, const float* __restrict__ bv,
    int N, int K)
{
  __shared__ alignas(16) char smem[33024];

  const int tid = threadIdx.x, lid = tid & 63, wid = tid >> 6;
  const int wm = wid >> 1, wn = wid & 1;
  const int g = lid >> 4, r16 = lid & 15;
  const int which = blockIdx.z;

  const u16* A = (which == 0) ? Aq : (which == 1) ? Ak : Av;
  const u16* B = (which == 0) ? Bq : (which == 1) ? Bk : Bv;
  u8* C = (which == 0) ? Cq : (which == 1) ? Ck : Cvv;
  const float* bias = (which == 0) ? bq : (which == 1) ? bk : bv;

  const int nx = gridDim.x, ny = gridDim.y;
  const int lin = blockIdx.x + nx * blockIdx.y;
  const int xcd = lin & 7, slot = lin >> 3;
  const int wx = slot % nx;
  const int c_ = xcd + (slot / nx) * 8;
  const int m0 = (c_ % ny) * 128, n0 = wx * 128;

  const int NT = K >> 5;

  int offA[4], offB[4];
#pragma unroll
  for (int f = 0; f < 4; ++f) {
    int ra = wm * 64 + f * 16 + r16;
    offA[f] = ra * 64 + ((g ^ ((ra >> 1) & 3)) << 4);
    int rb = wn * 64 + f * 16 + r16;
    offB[f] = rb * 64 + ((g ^ ((rb >> 1) & 3)) << 4);
  }

  auto stage_tile = [&](int ts) {
    char* base = smem + (ts & 1) * 16384;
    const u16* At = A + (size_t)ts * 32;
    const u16* Bt = B + (size_t)ts * 32;
#pragma unroll
    for (int l = 0; l < 2; ++l) {
      int i = l * 256 + tid;
      int row = i >> 2, x = i & 3;
      int c = x ^ ((row >> 1) & 3);
      gld_lds16(At + (size_t)(m0 + row) * K + c * 8, base + i * 16);
    }
#pragma unroll
    for (int l = 0; l < 2; ++l) {
      int i = l * 256 + tid;
      int row = i >> 2, x = i & 3;
      int c = x ^ ((row >> 1) & 3);
      gld_lds16(Bt + (size_t)(n0 + row) * K + c * 8, base + 8192 + i * 16);
    }
  };

  f32x4 acc[4][4];
#pragma unroll
  for (int i = 0; i < 4; ++i)
#pragma unroll
    for (int j = 0; j < 4; ++j) acc[i][j] = 0.0f;

  stage_tile(0);
  stage_tile(1);
  asm volatile("s_waitcnt vmcnt(4)" ::: "memory");
  __builtin_amdgcn_s_barrier();

  for (int t = 0; t < NT; ++t) {
    const char* Ab = smem + (t & 1) * 16384;
    const char* Bb = Ab + 8192;
    bf16x8 ar[4], br[4];
#pragma unroll
    for (int f = 0; f < 4; ++f) ar[f] = *(const bf16x8*)(Ab + offA[f]);
#pragma unroll
    for (int f = 0; f < 4; ++f) br[f] = *(const bf16x8*)(Bb + offB[f]);
    asm volatile("s_waitcnt lgkmcnt(0)" ::: "memory");
    __builtin_amdgcn_s_barrier();
    if (t + 2 < NT) stage_tile(t + 2);
    __builtin_amdgcn_s_setprio(1);
#pragma unroll
    for (int mf = 0; mf < 4; ++mf)
#pragma unroll
      for (int nf = 0; nf < 4; ++nf)
        acc[mf][nf] = __builtin_amdgcn_mfma_f32_16x16x32_bf16(ar[mf], br[nf], acc[mf][nf], 0, 0, 0);
    __builtin_amdgcn_s_setprio(0);
    if (t + 2 < NT) asm volatile("s_waitcnt vmcnt(4)" ::: "memory");
    else            asm volatile("s_waitcnt vmcnt(0)" ::: "memory");
    __builtin_amdgcn_s_barrier();
  }

  if (which < 2) {
    const int hh = (n0 + wn * 64) >> 9;
    const int d2g = (n0 & 511) + wn * 64;
#pragma unroll
    for (int mf = 0; mf < 4; ++mf)
#pragma unroll
      for (int r = 0; r < 4; ++r) {
        int gm = m0 + wm * 64 + mf * 16 + (g << 2) + r;
        int b = gm >> 9, s = gm & 511;
        float v0 = acc[mf][0][r] + bias[n0 + wn * 64 + 0 * 16 + r16];
        float v1 = acc[mf][1][r] + bias[n0 + wn * 64 + 1 * 16 + r16];
        float v2 = acc[mf][2][r] + bias[n0 + wn * 64 + 2 * 16 + r16];
        float v3 = acc[mf][3][r] + bias[n0 + wn * 64 + 3 * 16 + r16];
        int pk = __builtin_amdgcn_cvt_pk_fp8_f32(v0, v1, 0, false);
        pk = __builtin_amdgcn_cvt_pk_fp8_f32(v2, v3, pk, true);
        int row = (which == 0) ? ((s << 3) + hh) : ((hh << 9) + s);
        *(u32*)(C + (size_t)b * 2097152 + (size_t)row * 512 + d2g + r16 * 4) = (u32)pk;
      }
  } else {
    u16* E = (u16*)smem;   // 128 x 129 bf16
#pragma unroll
    for (int mf = 0; mf < 4; ++mf)
#pragma unroll
      for (int nf = 0; nf < 4; ++nf)
#pragma unroll
        for (int r = 0; r < 4; ++r) {
          int lm = wm * 64 + mf * 16 + (g << 2) + r;
          int ln = wn * 64 + nf * 16 + r16;
          E[lm * 129 + ln] = f2bf(acc[mf][nf][r] + bias[n0 + ln]);
        }
    __syncthreads();
    int b = m0 >> 9, s0 = m0 & 511, hh = n0 >> 9, d20 = n0 & 511;
    int c = tid >> 1;
    int r0 = (tid & 1) * 64;
    u8* dst = C + (size_t)b * 2097152 + (size_t)(d20 + c) * 4096 + (hh << 9) + s0 + r0;
#pragma unroll
    for (int i = 0; i < 64; i += 8) {
      u8x8 p;
#pragma unroll
      for (int jj = 0; jj < 8; ++jj) {
        int t = i + jj;
        int sl = r0 + ((t & 3) << 4) + (t >> 2);
        p[jj] = f2fp8(bf2f(E[sl * 129 + c]));
      }
      *(u8x8*)(dst + i) = p;
    }
  }
}

// =====================================================================
// fp8 pipelined 128x128 B^T GEMM — SCORES (proven: 74 µs, 0 conflicts).
// =====================================================================
__global__ __launch_bounds__(256, 4) void gemm_f8s(
    const u8* __restrict__ A, const u8* __restrict__ B, u8* __restrict__ Cv,
    float* __restrict__ Lbuf, int N, int K, float scale,
    long bsA, long bsB, long bsC)
{
  constexpr int SLOT = 256 * 64;
  __shared__ alignas(16) char smem[2 * SLOT];

  const int tid = threadIdx.x, lid = tid & 63, wid = tid >> 6;
  const int wm = wid >> 1, wn = wid & 1;
  const int g = lid >> 4, r16 = lid & 15;

  const int nx = gridDim.x, ny = gridDim.y;
  const int lin = blockIdx.x + nx * (blockIdx.y + ny * blockIdx.z);
  const int xcd = lin & 7, slot = lin >> 3;
  const int wx = slot % nx;
  const int c_ = xcd + (slot / nx) * 8;
  const int m0 = (c_ % ny) * 128, n0 = wx * 128, z = c_ / ny;

  A += (size_t)z * bsA;
  B += (size_t)z * bsB;
  const int NT = K >> 6;

  int offA[4], offB[4];
#pragma unroll
  for (int f = 0; f < 4; ++f) {
    int ra = wm * 64 + f * 16 + r16;
    offA[f] = ra * 64 + ((g ^ ((ra >> 1) & 3)) << 4);
    int rb = wn * 64 + f * 16 + r16;
    offB[f] = rb * 64 + ((g ^ ((rb >> 1) & 3)) << 4);
  }

  auto stage_tile = [&](int ts) {
    char* base = smem + (ts & 1) * SLOT;
    const u8* At = A + (size_t)ts * 64;
    const u8* Bt = B + (size_t)ts * 64;
#pragma unroll
    for (int l = 0; l < 2; ++l) {
      int i = l * 256 + tid;
      int row = i >> 2, x = i & 3;
      int c = x ^ ((row >> 1) & 3);
      gld_lds16(At + (size_t)(m0 + row) * K + c * 16, base + i * 16);
    }
#pragma unroll
    for (int l = 0; l < 2; ++l) {
      int i = l * 256 + tid;
      int row = i >> 2, x = i & 3;
      int c = x ^ ((row >> 1) & 3);
      gld_lds16(Bt + (size_t)(n0 + row) * K + c * 16, base + 8192 + i * 16);
    }
  };

  f32x4 acc[4][4];
#pragma unroll
  for (int i = 0; i < 4; ++i)
#pragma unroll
    for (int j = 0; j < 4; ++j) acc[i][j] = 0.0f;

  stage_tile(0);
  stage_tile(1);
  asm volatile("s_waitcnt vmcnt(4)" ::: "memory");
  __builtin_amdgcn_s_barrier();

  for (int t = 0; t < NT; ++t) {
    const char* Ab = smem + (t & 1) * SLOT;
    const char* Bb = Ab + 8192;
    lx2 ar[4], br[4];
#pragma unroll
    for (int f = 0; f < 4; ++f) ar[f] = *(const lx2*)(Ab + offA[f]);
#pragma unroll
    for (int f = 0; f < 4; ++f) br[f] = *(const lx2*)(Bb + offB[f]);
    asm volatile("s_waitcnt lgkmcnt(0)" ::: "memory");
    __builtin_amdgcn_s_barrier();
    if (t + 2 < NT) stage_tile(t + 2);
    __builtin_amdgcn_s_setprio(1);
#pragma unroll
    for (int mf = 0; mf < 4; ++mf)
#pragma unroll
      for (int nf = 0; nf < 4; ++nf) {
        acc[mf][nf] = __builtin_amdgcn_mfma_f32_16x16x32_fp8_fp8(ar[mf][0], br[nf][0], acc[mf][nf], 0, 0, 0);
        acc[mf][nf] = __builtin_amdgcn_mfma_f32_16x16x32_fp8_fp8(ar[mf][1], br[nf][1], acc[mf][nf], 0, 0, 0);
      }
    __builtin_amdgcn_s_setprio(0);
    if (t + 2 < NT) asm volatile("s_waitcnt vmcnt(4)" ::: "memory");
    else            asm volatile("s_waitcnt vmcnt(0)" ::: "memory");
    __builtin_amdgcn_s_barrier();
  }

  u8* Cp = Cv + (size_t)z * bsC;
  float* Lp = Lbuf + (size_t)z * 4096;
#pragma unroll
  for (int mf = 0; mf < 4; ++mf) {
#pragma unroll
    for (int r = 0; r < 4; ++r) {
      int gm = m0 + wm * 64 + mf * 16 + (g << 2) + r;
      float p0 = __expf(acc[mf][0][r] * scale);
      float p1 = __expf(acc[mf][1][r] * scale);
      float p2 = __expf(acc[mf][2][r] * scale);
      float p3 = __expf(acc[mf][3][r] * scale);
      float rs = (p0 + p1) + (p2 + p3);
      int pk = __builtin_amdgcn_cvt_pk_fp8_f32(p0, p1, 0, false);
      pk = __builtin_amdgcn_cvt_pk_fp8_f32(p2, p3, pk, true);
      *(u32*)(Cp + (size_t)gm * N + n0 + wn * 64 + r16 * 4) = (u32)pk;
      rs += __shfl_xor(rs, 1); rs += __shfl_xor(rs, 2);
      rs += __shfl_xor(rs, 4); rs += __shfl_xor(rs, 8);
      if (r16 == 0) atomicAdd(&Lp[gm], rs);
    }
  }
}

// =====================================================================
// MX-scaled fp8 pipelined 128x128 B^T GEMM — PV (proven ~30 µs).
// =====================================================================
__global__ __launch_bounds__(512, 4) void gemm_mx_pv(
    const u8* __restrict__ A, const u8* __restrict__ B, u16* __restrict__ Cv,
    const float* __restrict__ Lbuf, int N, int K,
    long bsA, long bsB, long bsC)
{
  __shared__ alignas(16) char smem[65536];

  const int tid = threadIdx.x, lid = tid & 63, wid = tid >> 6;
  const int wm = wid >> 1, wn = wid & 1;
  const int g = lid >> 4, r16 = lid & 15;

  const int nx = gridDim.x, ny = gridDim.y;
  const int lin = blockIdx.x + nx * (blockIdx.y + ny * blockIdx.z);
  const int xcd = lin & 7, slot = lin >> 3;
  const int wx = slot % nx;
  const int c_ = xcd + (slot / nx) * 8;
  const int m0 = (c_ % ny) * 128, n0 = wx * 128, z = c_ / ny;

  A += (size_t)z * bsA;
  B += (size_t)z * bsB;
  const int NT = K >> 7;

  int offA[2], offB[4];
#pragma unroll
  for (int f = 0; f < 2; ++f) {
    int ra = wm * 32 + f * 16 + r16;
    offA[f] = ra * 64 + ((g ^ ((ra >> 1) & 3)) << 4);
  }
#pragma unroll
  for (int f = 0; f < 4; ++f) {
    int rb = wn * 64 + f * 16 + r16;
    offB[f] = rb * 64 + ((g ^ ((rb >> 1) & 3)) << 4);
  }

  auto stage_tile = [&](int ts) {
    char* base = smem + (ts & 1) * 32768;
    const u8* At = A + (size_t)ts * 128;
    const u8* Bt = B + (size_t)ts * 128;
#pragma unroll
    for (int l = 0; l < 2; ++l) {
      int i = l * 512 + tid;
      int half = i >> 9, rem = i & 511, row = rem >> 2, x = rem & 3;
      int c = x ^ ((row >> 1) & 3);
      gld_lds16(At + (size_t)(m0 + row) * K + half * 64 + c * 16,
                base + half * 8192 + rem * 16);
    }
#pragma unroll
    for (int l = 0; l < 2; ++l) {
      int i = l * 512 + tid;
      int half = i >> 9, rem = i & 511, row = rem >> 2, x = rem & 3;
      int c = x ^ ((row >> 1) & 3);
      gld_lds16(Bt + (size_t)(n0 + row) * K + half * 64 + c * 16,
                base + 16384 + half * 8192 + rem * 16);
    }
  };

  f32x4 acc[2][4];
#pragma unroll
  for (int i = 0; i < 2; ++i)
#pragma unroll
    for (int j = 0; j < 4; ++j) acc[i][j] = 0.0f;

  stage_tile(0);
  stage_tile(1);
  asm volatile("s_waitcnt vmcnt(4)" ::: "memory");
  __builtin_amdgcn_s_barrier();

  for (int t = 0; t < NT; ++t) {
    const char* Ab = smem + (t & 1) * 32768;
    const char* Bb = Ab + 16384;
    i32x8 af[2], bfr[4];
#pragma unroll
    for (int f = 0; f < 2; ++f) {
      i32x4 lo = *(const i32x4*)(Ab + offA[f]);
      i32x4 hi = *(const i32x4*)(Ab + 8192 + offA[f]);
      af[f] = __builtin_shufflevector(lo, hi, 0, 1, 2, 3, 4, 5, 6, 7);
    }
#pragma unroll
    for (int f = 0; f < 4; ++f) {
      i32x4 lo = *(const i32x4*)(Bb + offB[f]);
      i32x4 hi = *(const i32x4*)(Bb + 8192 + offB[f]);
      bfr[f] = __builtin_shufflevector(lo, hi, 0, 1, 2, 3, 4, 5, 6, 7);
    }
    asm volatile("s_waitcnt lgkmcnt(0)" ::: "memory");
    __builtin_amdgcn_s_barrier();
    if (t + 2 < NT) stage_tile(t + 2);
    __builtin_amdgcn_s_setprio(1);
#pragma unroll
    for (int mf = 0; mf < 2; ++mf)
#pragma unroll
      for (int nf = 0; nf < 4; ++nf)
        acc[mf][nf] = __builtin_amdgcn_mfma_scale_f32_16x16x128_f8f6f4(
            af[mf], bfr[nf], acc[mf][nf],
            0, 0, 0, 0x7F7F7F7F, 0, 0x7F7F7F7F);
    __builtin_amdgcn_s_setprio(0);
    if (t + 2 < NT) asm volatile("s_waitcnt vmcnt(4)" ::: "memory");
    else            asm volatile("s_waitcnt vmcnt(0)" ::: "memory");
    __builtin_amdgcn_s_barrier();
  }

  u16* C = Cv + (size_t)z * bsC;
  const float* Lp = Lbuf + (size_t)z * 4096;
#pragma unroll
  for (int mf = 0; mf < 2; ++mf) {
#pragma unroll
    for (int r = 0; r < 4; ++r) {
      int gm = m0 + wm * 32 + mf * 16 + (g << 2) + r;
      float inv = 1.0f / Lp[gm];
      u16x4 o;
#pragma unroll
      for (int nf = 0; nf < 4; ++nf) o[nf] = f2bf(acc[mf][nf][r] * inv);
      *(u16x4*)(C + (size_t)(gm >> 3) * 4096 + (size_t)(gm & 7) * 512 +
                n0 + wn * 64 + r16 * 4) = o;
    }
  }
}

// =====================================================================
// FINAL projection, split-K=4: 128x128xK1024 per block, gemm_proj-style
// pipelined loop (K-tile 32, NT=32, issue-early, proven swizzle).
// grid (4,16,4) = 256 blocks.  f32 partials -> ws; reduced by fin_reduce.
// A = oflat (2048x4096 bf16, cols kv-permuted), B = ow_bf (512x4096,
// same permutation; chunk boundary 1024 = multiple of 64 -> consistent).
// =====================================================================
__global__ __launch_bounds__(256, 2) void gemm_fpart(
    const u16* __restrict__ A0, const u16* __restrict__ B0,
    float* __restrict__ part, int K)
{
  __shared__ alignas(16) char smem[32768];

  const int tid = threadIdx.x, lid = tid & 63, wid = tid >> 6;
  const int wm = wid >> 1, wn = wid & 1;
  const int g = lid >> 4, r16 = lid & 15;
  const int m0 = blockIdx.y * 128, n0 = blockIdx.x * 128, z = blockIdx.z;

  const u16* A = A0 + (size_t)z * 1024;   // K-chunk offset (row stride K)
  const u16* B = B0 + (size_t)z * 1024;
  constexpr int NT = 32;                  // 1024 / 32

  int offA[4], offB[4];
#pragma unroll
  for (int f = 0; f < 4; ++f) {
    int ra = wm * 64 + f * 16 + r16;
    offA[f] = ra * 64 + ((g ^ ((ra >> 1) & 3)) << 4);
    int rb = wn * 64 + f * 16 + r16;
    offB[f] = rb * 64 + ((g ^ ((rb >> 1) & 3)) << 4);
  }

  auto stage_tile = [&](int ts) {
    char* base = smem + (ts & 1) * 16384;
    const u16* At = A + (size_t)ts * 32;
    const u16* Bt = B + (size_t)ts * 32;
#pragma unroll
    for (int l = 0; l < 2; ++l) {
      int i = l * 256 + tid;
      int row = i >> 2, x = i & 3;
      int c = x ^ ((row >> 1) & 3);
      gld_lds16(At + (size_t)(m0 + row) * K + c * 8, base + i * 16);
    }
#pragma unroll
    for (int l = 0; l < 2; ++l) {
      int i = l * 256 + tid;
      int row = i >> 2, x = i & 3;
      int c = x ^ ((row >> 1) & 3);
      gld_lds16(Bt + (size_t)(n0 + row) * K + c * 8, base + 8192 + i * 16);
    }
  };

  f32x4 acc[4][4];
#pragma unroll
  for (int i = 0; i < 4; ++i)
#pragma unroll
    for (int j = 0; j < 4; ++j) acc[i][j] = 0.0f;

  stage_tile(0);
  stage_tile(1);
  asm volatile("s_waitcnt vmcnt(4)" ::: "memory");
  __builtin_amdgcn_s_barrier();

  for (int t = 0; t < NT; ++t) {
    const char* Ab = smem + (t & 1) * 16384;
    const char* Bb = Ab + 8192;
    bf16x8 ar[4], br[4];
#pragma unroll
    for (int f = 0; f < 4; ++f) ar[f] = *(const bf16x8*)(Ab + offA[f]);
#pragma unroll
    for (int f = 0; f < 4; ++f) br[f] = *(const bf16x8*)(Bb + offB[f]);
    asm volatile("s_waitcnt lgkmcnt(0)" ::: "memory");
    __builtin_amdgcn_s_barrier();
    if (t + 2 < NT) stage_tile(t + 2);
    __builtin_amdgcn_s_setprio(1);
#pragma unroll
    for (int mf = 0; mf < 4; ++mf)
#pragma unroll
      for (int nf = 0; nf < 4; ++nf)
        acc[mf][nf] = __builtin_amdgcn_mfma_f32_16x16x32_bf16(ar[mf], br[nf], acc[mf][nf], 0, 0, 0);
    __builtin_amdgcn_s_setprio(0);
    if (t + 2 < NT) asm volatile("s_waitcnt vmcnt(4)" ::: "memory");
    else            asm volatile("s_waitcnt vmcnt(0)" ::: "memory");
    __builtin_amdgcn_s_barrier();
  }

  float* P = part + ((size_t)z << 20);    // [z][2048][512]
#pragma unroll
  for (int mf = 0; mf < 4; ++mf)
#pragma unroll
    for (int nf = 0; nf < 4; ++nf)
#pragma unroll
      for (int r = 0; r < 4; ++r) {
        int gm = m0 + wm * 64 + mf * 16 + (g << 2) + r;
        int gn = n0 + wn * 64 + nf * 16 + r16;
        P[(size_t)gm * 512 + gn] = acc[mf][nf][r];
      }
}

// ---- reduce 4 partials + bias -> out (f32), 4 elems/thread ----
__global__ __launch_bounds__(256) void fin_reduce(
    const float* __restrict__ part, const float* __restrict__ bias,
    float* __restrict__ out)
{
  int i = (blockIdx.x * 256 + threadIdx.x) * 4;
  f32x4 s = *(const f32x4*)(part + i);
  s += *(const f32x4*)(part + 1048576 + i);
  s += *(const f32x4*)(part + 2097152 + i);
  s += *(const f32x4*)(part + 3145728 + i);
  s += *(const f32x4*)(bias + (i & 511));
  *(f32x4*)(out + i) = s;
}

// ---------------------------------------------------------------------------
extern "C" void kernel_launch(void* const* d_in, const int* in_sizes, int n_in,
                              void* d_out, int out_size, void* d_ws, size_t ws_size,
                              hipStream_t stream) {
  (void)in_sizes; (void)n_in; (void)out_size; (void)ws_size;
  const float* q_f  = (const float*)d_in[0];
  const float* k_f  = (const float*)d_in[1];
  const float* v_f  = (const float*)d_in[2];
  const float* wq_b = (const float*)d_in[4];
  const float* wk_b = (const float*)d_in[6];
  const float* wv_b = (const float*)d_in[8];
  const float* ou_b = (const float*)d_in[10];
  float* out = (float*)d_out;

  char* ws = (char*)d_ws;
  u16* q_bf  = (u16*)(ws + 0);          // 2MB  bf16(q)
  u16* k_bf  = (u16*)(ws + 2097152);    // 2MB
  u16* v_bf  = (u16*)(ws + 4194304);    // 2MB
  u16* wA_q  = (u16*)(ws + 6291456);    // 4MB  bf16(wk_w) (reference swap)
  u16* wA_k  = (u16*)(ws + 10485760);   // 4MB  bf16(wq_w)
  u16* wA_v  = (u16*)(ws + 14680064);   // 4MB  bf16(wv_w)
  u16* ow_bf = (u16*)(ws + 18874368);   // 4MB  bf16(out_w), K within-64 permuted
  u8*  qp    = (u8*)(ws + 23068672);    // 8MB  (4,4096,512) fp8, l=s*8+h, d2 permuted
  u8*  kp    = (u8*)(ws + 31457280);    // 8MB  (4,4096,512) fp8, l'=h*512+s, d2 permuted
  u8*  vpt   = (u8*)(ws + 39845888);    // 8MB  (4,512,4096) fp8, [d2][kv-permuted]
  u16* oflat = (u16*)(ws + 48234496);   // 16MB (4,512,4096) bf16, cols within-64 permuted
  u8*  P     = (u8*)(ws + 65011712);    // 64MB (4,4096,4096) fp8, cols kv-permuted
  float* fpt = (float*)(ws + 132120576);// 16MB (4,2048,512) f32 split-K partials

  float* L = (float*)d_out;  // 64KB row-sums; dead until fin_reduce overwrites

  // all converts + L-zero in one launch
  cvt_all<<<5633, 256, 0, stream>>>(
      q_f, k_f, v_f, (const float*)d_in[5], (const float*)d_in[3],
      (const float*)d_in[7], (const float*)d_in[9],
      q_bf, k_bf, v_bf, wA_q, wA_k, wA_v, ow_bf, L);

  // all three projections in one launch (reference swap: qp uses wk, kp uses wq)
  gemm_proj<<<dim3(32,16,3), 256, 0, stream>>>(
      q_bf, k_bf, v_bf, wA_q, wA_k, wA_v, qp, kp, vpt, wk_b, wq_b, wv_b, 4096, 512);

  const float scl = 0.04419417382415922f;  // 1/sqrt(512)
  // scores: P = exp(s*scl) fp8 (kv-permuted) + row-sums into L  (fp8, NT=8)
  gemm_f8s<<<dim3(32,32,4), 256, 0, stream>>>(qp, kp, P, L, 4096, 512, scl,
                                              2097152, 2097152, 16777216);
  // PV: O = (P @ V) / L -> oflat bf16  (MX fp8, K=128, NT=32)
  gemm_mx_pv<<<dim3(4,32,4), 512, 0, stream>>>(P, vpt, oflat, L, 512, 4096,
                                               16777216, 2097152, 2097152);
  // final projection: split-K=4 partials, then reduce + bias
  gemm_fpart<<<dim3(4,16,4), 256, 0, stream>>>(oflat, ow_bf, fpt, 4096);
  fin_reduce<<<1024, 256, 0, stream>>>(fpt, ou_b, out);
}